// Round 12
// baseline (108.905 us; speedup 1.0000x reference)
//
#include <hip/hip_runtime.h>

typedef __attribute__((ext_vector_type(8))) short short8_t;
typedef __attribute__((ext_vector_type(4))) float f32x4;

namespace {
constexpr int T_CTX  = 4096;
constexpr int E_DIM  = 1024;
constexpr int H_DIM  = 64;
constexpr int B_SZ   = 4;
constexpr int M_ROWS = B_SZ * T_CTX; // 16384
// 1/sqrt(H) * log2(e): S lands in log2 domain -> softmax via exp2
constexpr float SCALE_Q = 0.125f * 1.4426950408889634f;
constexpr float DEFER_THR = 8.0f;    // log2 units; P bounded by 2^8
constexpr int NCID = 320;            // 16-tile chunks per batch: sum(st/32+1)
}

__device__ __forceinline__ unsigned short f2bf(float f) {
    unsigned u = __builtin_bit_cast(unsigned, f);
    u += 0x7fffu + ((u >> 16) & 1u);          // RNE
    return (unsigned short)(u >> 16);
}
__device__ __forceinline__ unsigned pack2(unsigned short lo, unsigned short hi) {
    return (unsigned)lo | ((unsigned)hi << 16);
}
__device__ __forceinline__ unsigned cvtpk(float lo, float hi) {
    unsigned r;
    asm("v_cvt_pk_bf16_f32 %0, %1, %2" : "=v"(r) : "v"(lo), "v"(hi));
    return r;
}
__device__ __forceinline__ float fexp2(float x) {   // guaranteed v_exp_f32
    float r;
    asm("v_exp_f32 %0, %1" : "=v"(r) : "v"(x));
    return r;
}
// swizzled ushort index into a row-major [rows][64] bf16 LDS tile
__device__ __forceinline__ int swz(int row, int col) {
    return row * 64 + (col ^ ((row & 7) << 3));
}

// ---------------------------------------------------------------------------
// Weight prep: W[1024][64] fp32 -> FRAGMENT-MAJOR bf16 layout (1KB streams).
// ---------------------------------------------------------------------------
__global__ __launch_bounds__(256)
void prep_weights(const float* __restrict__ Wq, const float* __restrict__ Wk,
                  const float* __restrict__ Wv, unsigned short* __restrict__ wt)
{
    const int mat = blockIdx.y;
    const int kc  = blockIdx.x;
    const float* W = (mat == 0) ? Wq : (mat == 1) ? Wk : Wv;
    __shared__ float Ls[64][65];   // Ls[n][k_local]
    const int tid = threadIdx.x;
    const int kb = kc * 64;
    #pragma unroll
    for (int j = 0; j < 4; ++j) {
        int p = j * 256 + tid;
        int kr = p >> 4, c4 = (p & 15) * 4;
        float4 w4 = *reinterpret_cast<const float4*>(&W[(size_t)(kb + kr) * H_DIM + c4]);
        Ls[c4 + 0][kr] = w4.x; Ls[c4 + 1][kr] = w4.y;
        Ls[c4 + 2][kr] = w4.z; Ls[c4 + 3][kr] = w4.w;
    }
    __syncthreads();
    #pragma unroll
    for (int j = 0; j < 2; ++j) {
        int p = j * 256 + tid;       // 0..511
        int f  = p >> 6;             // 0..7 = oc*2 + hs
        int ln = p & 63;
        int n   = (f >> 1) * 16 + (ln & 15);
        int kb8 = (f & 1) * 32 + (ln >> 4) * 8;
        uint4 w;
        w.x = pack2(f2bf(Ls[n][kb8 + 0]), f2bf(Ls[n][kb8 + 1]));
        w.y = pack2(f2bf(Ls[n][kb8 + 2]), f2bf(Ls[n][kb8 + 3]));
        w.z = pack2(f2bf(Ls[n][kb8 + 4]), f2bf(Ls[n][kb8 + 5]));
        w.w = pack2(f2bf(Ls[n][kb8 + 6]), f2bf(Ls[n][kb8 + 7]));
        size_t off = ((size_t)(kc * 24 + mat * 8 + f) * 64 + ln) * 8;
        *reinterpret_cast<uint4*>(&wt[off]) = w;
    }
}

// ---------------------------------------------------------------------------
// Fused QKV projection (unchanged).
// ---------------------------------------------------------------------------
__global__ __launch_bounds__(512, 1)
void proj_kernel(const float* __restrict__ x, const unsigned short* __restrict__ wt,
                 const float* __restrict__ bq, const float* __restrict__ bk,
                 const float* __restrict__ bv,
                 unsigned short* __restrict__ qb, unsigned short* __restrict__ kb,
                 unsigned short* __restrict__ vtb)
{
    const int tid = threadIdx.x;
    const int lane = tid & 63, wv = tid >> 6;   // wv 0..7
    const int l15 = lane & 15, lg = lane >> 4;
    const int kof = lg * 8;

    const int rg = wv & 3;                      // row-group
    const int kh = wv >> 2;                     // k-half
    const int m0    = blockIdx.x * 64 + rg * 16;
    const int batch = m0 >> 12;
    const int t0    = m0 & (T_CTX - 1);
    const int kbeg  = kh * 512;

    f32x4 acc[3][4] = {};
    const float* xrow = &x[(size_t)(m0 + l15) * E_DIM + kof];
    const unsigned short* wlane = wt + (size_t)lane * 8;   // lane-folded

    float4 xa0 = *reinterpret_cast<const float4*>(xrow + kbeg);
    float4 xb0 = *reinterpret_cast<const float4*>(xrow + kbeg + 4);
    float4 xa1 = *reinterpret_cast<const float4*>(xrow + kbeg + 32);
    float4 xb1 = *reinterpret_cast<const float4*>(xrow + kbeg + 36);

    for (int k0 = kbeg; k0 < kbeg + 512; k0 += 32) {
        const int kn = (k0 + 64 < kbeg + 512) ? k0 + 64 : kbeg;
        float4 na = *reinterpret_cast<const float4*>(xrow + kn);
        float4 nb = *reinterpret_cast<const float4*>(xrow + kn + 4);

        const int fb = (k0 >> 6) * 24 + ((k0 >> 5) & 1);
        short8_t bf[12];
        #pragma unroll
        for (int mat = 0; mat < 3; ++mat)
            #pragma unroll
            for (int oc = 0; oc < 4; ++oc)
                bf[mat * 4 + oc] = *reinterpret_cast<const short8_t*>(
                    wlane + (size_t)(fb + mat * 8 + oc * 2) * 512);

        uint4 au;
        au.x = cvtpk(xa0.x, xa0.y); au.y = cvtpk(xa0.z, xa0.w);
        au.z = cvtpk(xb0.x, xb0.y); au.w = cvtpk(xb0.z, xb0.w);
        const short8_t a = __builtin_bit_cast(short8_t, au);

        #pragma unroll
        for (int mat = 0; mat < 3; ++mat)
            #pragma unroll
            for (int oc = 0; oc < 4; ++oc)
                acc[mat][oc] = __builtin_amdgcn_mfma_f32_16x16x32_bf16(
                    a, bf[mat * 4 + oc], acc[mat][oc], 0, 0, 0);

        xa0 = xa1; xb0 = xb1; xa1 = na; xb1 = nb;
    }

    __shared__ float Ms[4][64][49];              // 50 KB fp32 merge
    __shared__ unsigned short Stg[4][1024];      // 8 KB bf16 staging (NO alias)
    if (kh == 1) {
        #pragma unroll
        for (int mat = 0; mat < 3; ++mat)
            #pragma unroll
            for (int oc = 0; oc < 4; ++oc)
                #pragma unroll
                for (int r = 0; r < 4; ++r)
                    Ms[rg][lane][(mat * 4 + oc) * 4 + r] = acc[mat][oc][r];
    }
    __syncthreads();
    if (kh == 0) {
        #pragma unroll
        for (int mat = 0; mat < 3; ++mat)
            #pragma unroll
            for (int oc = 0; oc < 4; ++oc)
                #pragma unroll
                for (int r = 0; r < 4; ++r)
                    acc[mat][oc][r] += Ms[rg][lane][(mat * 4 + oc) * 4 + r];

        unsigned short* stage = &Stg[rg][0];

        #pragma unroll
        for (int mat = 0; mat < 2; ++mat) {
            const float* bias = mat ? bk : bq;
            const float sc = mat ? 1.0f : SCALE_Q;
            #pragma unroll
            for (int oc = 0; oc < 4; ++oc) {
                const float bb = bias[oc * 16 + l15];
                #pragma unroll
                for (int r = 0; r < 4; ++r)
                    stage[swz(lg * 4 + r, oc * 16 + l15)] =
                        f2bf((acc[mat][oc][r] + bb) * sc);
            }
            unsigned short* outg = mat ? kb : qb;
            const int row = lane >> 2, c = (lane & 3) * 16;
            uint4 w0 = *reinterpret_cast<const uint4*>(&stage[swz(row, c)]);
            uint4 w1 = *reinterpret_cast<const uint4*>(&stage[swz(row, c + 8)]);
            *reinterpret_cast<uint4*>(&outg[(size_t)(m0 + row) * H_DIM + c]) = w0;
            *reinterpret_cast<uint4*>(&outg[(size_t)(m0 + row) * H_DIM + c + 8]) = w1;
        }

        #pragma unroll
        for (int oc = 0; oc < 4; ++oc) {
            const float bb = bv[oc * 16 + l15];
            const int h = oc * 16 + l15;
            uint2 pw;
            pw.x = cvtpk(acc[2][oc][0] + bb, acc[2][oc][1] + bb);
            pw.y = cvtpk(acc[2][oc][2] + bb, acc[2][oc][3] + bb);
            *reinterpret_cast<uint2*>(&stage[h * 16 + lg * 4]) = pw;
        }
        const int h = lane;
        uint4 v0 = *reinterpret_cast<const uint4*>(&stage[h * 16]);
        uint4 v1 = *reinterpret_cast<const uint4*>(&stage[h * 16 + 8]);
        unsigned short* vrow = &vtb[((size_t)batch * H_DIM + h) * T_CTX + t0];
        *reinterpret_cast<uint4*>(&vrow[0]) = v0;
        *reinterpret_cast<uint4*>(&vrow[8]) = v1;
    }
}

// ---------------------------------------------------------------------------
// Causal flash attention, PERSISTENT blocks + grid-stride over the flat
// chunk list. 512 blocks (= the 16-wave/CU VGPR residency cap, 2 blocks/CU)
// stay resident and stride u += 512 through 1280 heavy-first units.
// Unit = 16-tile kv chunk of a 32-row strip; 8 waves split it (<=2 tiles
// each). V loads hoisted before softmax (latency hidden). One barrier per
// unit fences the aliased Pt/merge LDS.
// ---------------------------------------------------------------------------
__global__ __launch_bounds__(512, 4)
void attn_kernel(const unsigned short* __restrict__ qg,
                 const unsigned short* __restrict__ kg,
                 const unsigned short* __restrict__ vt,
                 float* __restrict__ outp,
                 float* __restrict__ po, float* __restrict__ pm,
                 float* __restrict__ pl)
{
    const int tid  = threadIdx.x;
    const int lane = tid & 63, wv = tid >> 6;   // wv 0..7
    const int l15 = lane & 15, lg = lane >> 4;
    const int kof = lg * 8;

    __shared__ float smem[8448];                // Pt (32KB) ∪ merge (33KB)
    unsigned short* Pt = (unsigned short*)smem;
    const int pbase = wv * 2048;                // per-wave [32][64] bf16

    for (int u = blockIdx.x; u < 4 * NCID; u += gridDim.x) {
        const int idx   = 4 * NCID - 1 - u;     // heavy chunks first
        const int batch = idx & 3;
        const int cid   = idx >> 2;             // 0..319
        int g;
        if (cid < 32) g = 0; else if (cid < 96) g = 1; else if (cid < 192) g = 2; else g = 3;
        const int rem = cid - 16 * g * (g + 1);
        int st, chunk;
        switch (g) {
            case 0:  st = rem;             chunk = 0;              break;
            case 1:  st = 32 + (rem >> 1); chunk = rem & 1;        break;
            case 2:  st = 64 + rem / 3;    chunk = rem - 3 * (rem / 3); break;
            default: st = 96 + (rem >> 2); chunk = rem & 3;        break;
        }
        const int cc   = g + 1;
        const int q0   = st * 32;
        const int nkv  = st / 2 + 1;            // 64-wide kv tiles in strip
        const int tbeg = chunk * 16 + wv;
        const int tcap = chunk * 16 + 16;
        const int tend = (tcap < nkv) ? tcap : nkv;
        const int pidx = batch * NCID + cid;
        const size_t rbase = (size_t)batch * T_CTX;
        const size_t vbase = (size_t)batch * H_DIM * T_CTX;

        __syncthreads();   // previous unit's merge reads done before Pt reuse

        short8_t qlo[2], qhi[2];
        #pragma unroll
        for (int hs = 0; hs < 2; ++hs) {
            qlo[hs] = *reinterpret_cast<const short8_t*>(
                &qg[(rbase + q0 + l15) * H_DIM + hs * 32 + kof]);
            qhi[hs] = *reinterpret_cast<const short8_t*>(
                &qg[(rbase + q0 + 16 + l15) * H_DIM + hs * 32 + kof]);
        }

        f32x4 olo[4] = {}, ohi[4] = {};
        float mlo = -1e30f, mhi = -1e30f, llo = 0.f, lhi = 0.f;

        for (int t = tbeg; t < tend; t += 8) {
            const int k0 = t * 64;
            const unsigned short* kp = kg + (rbase + k0 + l15) * H_DIM + kof;
            const unsigned short* vp = vt + vbase + (size_t)l15 * T_CTX + k0 + kof;

            f32x4 slo[4] = {}, shi[4] = {};
            #pragma unroll
            for (int hs = 0; hs < 2; ++hs) {
                short8_t kf[4];
                #pragma unroll
                for (int ct = 0; ct < 4; ++ct)
                    kf[ct] = *reinterpret_cast<const short8_t*>(kp + ct * 16 * H_DIM + hs * 32);
                #pragma unroll
                for (int ct = 0; ct < 4; ++ct) {
                    slo[ct] = __builtin_amdgcn_mfma_f32_16x16x32_bf16(kf[ct], qlo[hs], slo[ct], 0, 0, 0);
                    shi[ct] = __builtin_amdgcn_mfma_f32_16x16x32_bf16(kf[ct], qhi[hs], shi[ct], 0, 0, 0);
                }
            }

            // V fragments issued EARLY (independent of softmax -> latency hidden)
            short8_t vf[8];
            #pragma unroll
            for (int oc = 0; oc < 4; ++oc)
                #pragma unroll
                for (int ks = 0; ks < 2; ++ks)
                    vf[oc * 2 + ks] = *reinterpret_cast<const short8_t*>(
                        vp + (size_t)(oc * 16) * T_CTX + ks * 32);

            if (t == nkv - 1) {   // only the strip's last tile crosses the diagonal
                #pragma unroll
                for (int ct = 0; ct < 4; ++ct)
                    #pragma unroll
                    for (int r = 0; r < 4; ++r) {
                        const int kv = k0 + ct * 16 + lg * 4 + r;
                        if (kv > q0 + l15)      slo[ct][r] = -1e30f;
                        if (kv > q0 + 16 + l15) shi[ct][r] = -1e30f;
                    }
            }

            float mxlo, mxhi;
            {
                float a = fmaxf(fmaxf(slo[0][0], slo[0][1]), fmaxf(slo[0][2], slo[0][3]));
                float b = fmaxf(fmaxf(slo[1][0], slo[1][1]), fmaxf(slo[1][2], slo[1][3]));
                float c = fmaxf(fmaxf(slo[2][0], slo[2][1]), fmaxf(slo[2][2], slo[2][3]));
                float d = fmaxf(fmaxf(slo[3][0], slo[3][1]), fmaxf(slo[3][2], slo[3][3]));
                mxlo = fmaxf(fmaxf(a, b), fmaxf(c, d));
                a = fmaxf(fmaxf(shi[0][0], shi[0][1]), fmaxf(shi[0][2], shi[0][3]));
                b = fmaxf(fmaxf(shi[1][0], shi[1][1]), fmaxf(shi[1][2], shi[1][3]));
                c = fmaxf(fmaxf(shi[2][0], shi[2][1]), fmaxf(shi[2][2], shi[2][3]));
                d = fmaxf(fmaxf(shi[3][0], shi[3][1]), fmaxf(shi[3][2], shi[3][3]));
                mxhi = fmaxf(fmaxf(a, b), fmaxf(c, d));
            }
            mxlo = fmaxf(mxlo, __shfl_xor(mxlo, 16));
            mxlo = fmaxf(mxlo, __shfl_xor(mxlo, 32));
            mxhi = fmaxf(mxhi, __shfl_xor(mxhi, 16));
            mxhi = fmaxf(mxhi, __shfl_xor(mxhi, 32));

            if (!__all((mxlo <= mlo + DEFER_THR) && (mxhi <= mhi + DEFER_THR))) {
                const float nmlo = fmaxf(mlo, mxlo), nmhi = fmaxf(mhi, mxhi);
                const float cflo = fexp2(mlo - nmlo), cfhi = fexp2(mhi - nmhi);
                llo *= cflo; lhi *= cfhi;
                mlo = nmlo; mhi = nmhi;
                #pragma unroll
                for (int r = 0; r < 4; ++r) {
                    const float cl = __shfl(cflo, lg * 4 + r);
                    const float ch = __shfl(cfhi, lg * 4 + r);
                    #pragma unroll
                    for (int oc = 0; oc < 4; ++oc) { olo[oc][r] *= cl; ohi[oc][r] *= ch; }
                }
            }

            float rllo = 0.f, rlhi = 0.f;
            #pragma unroll
            for (int ct = 0; ct < 4; ++ct) {
                const float p0 = fexp2(slo[ct][0] - mlo), p1 = fexp2(slo[ct][1] - mlo);
                const float p2 = fexp2(slo[ct][2] - mlo), p3 = fexp2(slo[ct][3] - mlo);
                rllo += (p0 + p1) + (p2 + p3);
                uint2 pw; pw.x = cvtpk(p0, p1); pw.y = cvtpk(p2, p3);
                *reinterpret_cast<uint2*>(&Pt[pbase + swz(l15, ct * 16 + lg * 4)]) = pw;
                const float h0 = fexp2(shi[ct][0] - mhi), h1 = fexp2(shi[ct][1] - mhi);
                const float h2 = fexp2(shi[ct][2] - mhi), h3 = fexp2(shi[ct][3] - mhi);
                rlhi += (h0 + h1) + (h2 + h3);
                uint2 ph; ph.x = cvtpk(h0, h1); ph.y = cvtpk(h2, h3);
                *reinterpret_cast<uint2*>(&Pt[pbase + swz(16 + l15, ct * 16 + lg * 4)]) = ph;
            }
            rllo += __shfl_xor(rllo, 16); rllo += __shfl_xor(rllo, 32);
            rlhi += __shfl_xor(rlhi, 16); rlhi += __shfl_xor(rlhi, 32);
            llo += rllo; lhi += rlhi;

            #pragma unroll
            for (int ks = 0; ks < 2; ++ks) {
                const short8_t palo = *reinterpret_cast<const short8_t*>(
                    &Pt[pbase + swz(l15, ks * 32 + kof)]);
                const short8_t pahi = *reinterpret_cast<const short8_t*>(
                    &Pt[pbase + swz(16 + l15, ks * 32 + kof)]);
                #pragma unroll
                for (int oc = 0; oc < 4; ++oc) {
                    olo[oc] = __builtin_amdgcn_mfma_f32_16x16x32_bf16(palo, vf[oc * 2 + ks], olo[oc], 0, 0, 0);
                    ohi[oc] = __builtin_amdgcn_mfma_f32_16x16x32_bf16(pahi, vf[oc * 2 + ks], ohi[oc], 0, 0, 0);
                }
            }
        }

        // ---- two-phase chunk merge: phase 0 = lo rows, phase 1 = hi rows ----
        #pragma unroll
        for (int ph = 0; ph < 2; ++ph) {
            __syncthreads();
            #pragma unroll
            for (int oc = 0; oc < 4; ++oc)
                #pragma unroll
                for (int r = 0; r < 4; ++r)
                    smem[wv * 1024 + (lg * 4 + r) * 64 + oc * 16 + l15] =
                        ph ? ohi[oc][r] : olo[oc][r];
            if (lg == 0) {
                smem[8192 + wv * 16 + l15] = ph ? mhi : mlo;
                smem[8320 + wv * 16 + l15] = ph ? lhi : llo;
            }
            __syncthreads();
            const int row = tid >> 5;          // 0..15
            const int c2  = (tid & 31) * 2;
            float M = -1e30f;
            #pragma unroll
            for (int w = 0; w < 8; ++w) M = fmaxf(M, smem[8192 + w * 16 + row]);
            float L = 0.f, a0 = 0.f, a1 = 0.f;
            #pragma unroll
            for (int w = 0; w < 8; ++w) {
                const float e = fexp2(smem[8192 + w * 16 + row] - M);
                L += e * smem[8320 + w * 16 + row];
                a0 += e * smem[w * 1024 + row * 64 + c2];
                a1 += e * smem[w * 1024 + row * 64 + c2 + 1];
            }
            if (cc == 1) {
                const float inv = 1.0f / L;
                float2 rr; rr.x = a0 * inv; rr.y = a1 * inv;
                *reinterpret_cast<float2*>(
                    &outp[(rbase + q0 + ph * 16 + row) * H_DIM + c2]) = rr;
            } else {
                float2 rr; rr.x = a0; rr.y = a1;
                *reinterpret_cast<float2*>(
                    &po[(size_t)pidx * 2048 + (ph * 16 + row) * 64 + c2]) = rr;
                if (c2 == 0) {
                    pm[(size_t)pidx * 32 + ph * 16 + row] = M;
                    pl[(size_t)pidx * 32 + ph * 16 + row] = L;
                }
            }
        }
    }
}

// ---------------------------------------------------------------------------
// Fixup: combine 2..4 chunk partials per (strip st>=32, batch) via LSE.
// ---------------------------------------------------------------------------
__global__ __launch_bounds__(256)
void fixup_kernel(const float* __restrict__ po, const float* __restrict__ pm,
                  const float* __restrict__ pl, float* __restrict__ outp)
{
    const int sb    = blockIdx.x;      // 0..383
    const int st    = 32 + (sb >> 2);  // 32..127
    const int batch = sb & 3;
    const int g     = st >> 5;         // 1..3
    const int cc    = g + 1;
    const int cid0  = cc * (st - 16 * g);
    const int pb0   = batch * NCID + cid0;
    const int tid   = threadIdx.x;
    const int row   = tid >> 3;        // 0..31
    const int c8    = (tid & 7) * 8;

    float M = -1e30f;
    for (int c = 0; c < cc; ++c)
        M = fmaxf(M, pm[(size_t)(pb0 + c) * 32 + row]);
    float L = 0.f;
    float a[8] = {};
    for (int c = 0; c < cc; ++c) {
        const float e = fexp2(pm[(size_t)(pb0 + c) * 32 + row] - M);
        L += e * pl[(size_t)(pb0 + c) * 32 + row];
        const float4 v0 = *reinterpret_cast<const float4*>(
            &po[(size_t)(pb0 + c) * 2048 + row * 64 + c8]);
        const float4 v1 = *reinterpret_cast<const float4*>(
            &po[(size_t)(pb0 + c) * 2048 + row * 64 + c8 + 4]);
        a[0] += e * v0.x; a[1] += e * v0.y; a[2] += e * v0.z; a[3] += e * v0.w;
        a[4] += e * v1.x; a[5] += e * v1.y; a[6] += e * v1.z; a[7] += e * v1.w;
    }
    const float inv = 1.0f / L;
    float4 r0, r1;
    r0.x = a[0] * inv; r0.y = a[1] * inv; r0.z = a[2] * inv; r0.w = a[3] * inv;
    r1.x = a[4] * inv; r1.y = a[5] * inv; r1.z = a[6] * inv; r1.w = a[7] * inv;
    float* orow = &outp[((size_t)batch * T_CTX + st * 32 + row) * H_DIM + c8];
    *reinterpret_cast<float4*>(orow)     = r0;
    *reinterpret_cast<float4*>(orow + 4) = r1;
}

extern "C" void kernel_launch(void* const* d_in, const int* in_sizes, int n_in,
                              void* d_out, int out_size, void* d_ws, size_t ws_size,
                              hipStream_t stream) {
    const float* x  = (const float*)d_in[0];
    const float* Wq = (const float*)d_in[1];
    const float* bq = (const float*)d_in[2];
    const float* Wk = (const float*)d_in[3];
    const float* bk = (const float*)d_in[4];
    const float* Wv = (const float*)d_in[5];
    const float* bv = (const float*)d_in[6];
    float* out = (float*)d_out;

    // ws: ushort wt|q|k|vt (6.7 MB) then f32 partials po|pm|pl (~10.8 MB)
    unsigned short* wt  = (unsigned short*)d_ws;
    unsigned short* qb  = wt + 3 * H_DIM * E_DIM;
    unsigned short* kb  = qb + (size_t)M_ROWS * H_DIM;
    unsigned short* vtb = kb + (size_t)M_ROWS * H_DIM;
    float* po = (float*)(vtb + (size_t)B_SZ * H_DIM * T_CTX);
    float* pm = po + (size_t)4 * NCID * 2048;
    float* pl = pm + (size_t)4 * NCID * 32;

    prep_weights<<<dim3(E_DIM / 64, 3), 256, 0, stream>>>(Wq, Wk, Wv, wt);
    proj_kernel<<<dim3(M_ROWS / 64), 512, 0, stream>>>(x, wt, bq, bk, bv, qb, kb, vtb);
    attn_kernel<<<dim3(512), 512, 0, stream>>>(qb, kb, vtb, out, po, pm, pl);
    fixup_kernel<<<dim3(384), 256, 0, stream>>>(po, pm, pl, out);
}

// Round 13
// 70.024 us; speedup vs baseline: 1.5553x; 1.5553x over previous
//
#include <hip/hip_runtime.h>

typedef __attribute__((ext_vector_type(8))) short short8_t;
typedef __attribute__((ext_vector_type(4))) float f32x4;

namespace {
constexpr int T_CTX  = 4096;
constexpr int E_DIM  = 1024;
constexpr int H_DIM  = 64;
constexpr int B_SZ   = 4;
constexpr int M_ROWS = B_SZ * T_CTX; // 16384
// 1/sqrt(H) * log2(e): S lands in log2 domain -> softmax via exp2
constexpr float SCALE_Q = 0.125f * 1.4426950408889634f;
constexpr float DEFER_THR = 8.0f;    // log2 units; P bounded by 2^8
}

__device__ __forceinline__ unsigned short f2bf(float f) {
    unsigned u = __builtin_bit_cast(unsigned, f);
    u += 0x7fffu + ((u >> 16) & 1u);          // RNE
    return (unsigned short)(u >> 16);
}
__device__ __forceinline__ unsigned pack2(unsigned short lo, unsigned short hi) {
    return (unsigned)lo | ((unsigned)hi << 16);
}
__device__ __forceinline__ unsigned cvtpk(float lo, float hi) {
    unsigned r;
    asm("v_cvt_pk_bf16_f32 %0, %1, %2" : "=v"(r) : "v"(lo), "v"(hi));
    return r;
}
__device__ __forceinline__ float fexp2(float x) {   // guaranteed v_exp_f32
    float r;
    asm("v_exp_f32 %0, %1" : "=v"(r) : "v"(x));
    return r;
}
// swizzled ushort index into a row-major [rows][64] bf16 LDS tile
__device__ __forceinline__ int swz(int row, int col) {
    return row * 64 + (col ^ ((row & 7) << 3));
}

// ---------------------------------------------------------------------------
// Weight prep: W[1024][64] fp32 -> FRAGMENT-MAJOR bf16 layout (1KB streams).
// ---------------------------------------------------------------------------
__global__ __launch_bounds__(256)
void prep_weights(const float* __restrict__ Wq, const float* __restrict__ Wk,
                  const float* __restrict__ Wv, unsigned short* __restrict__ wt)
{
    const int mat = blockIdx.y;
    const int kc  = blockIdx.x;
    const float* W = (mat == 0) ? Wq : (mat == 1) ? Wk : Wv;
    __shared__ float Ls[64][65];   // Ls[n][k_local]
    const int tid = threadIdx.x;
    const int kb = kc * 64;
    #pragma unroll
    for (int j = 0; j < 4; ++j) {
        int p = j * 256 + tid;
        int kr = p >> 4, c4 = (p & 15) * 4;
        float4 w4 = *reinterpret_cast<const float4*>(&W[(size_t)(kb + kr) * H_DIM + c4]);
        Ls[c4 + 0][kr] = w4.x; Ls[c4 + 1][kr] = w4.y;
        Ls[c4 + 2][kr] = w4.z; Ls[c4 + 3][kr] = w4.w;
    }
    __syncthreads();
    #pragma unroll
    for (int j = 0; j < 2; ++j) {
        int p = j * 256 + tid;       // 0..511
        int f  = p >> 6;             // 0..7 = oc*2 + hs
        int ln = p & 63;
        int n   = (f >> 1) * 16 + (ln & 15);
        int kb8 = (f & 1) * 32 + (ln >> 4) * 8;
        uint4 w;
        w.x = pack2(f2bf(Ls[n][kb8 + 0]), f2bf(Ls[n][kb8 + 1]));
        w.y = pack2(f2bf(Ls[n][kb8 + 2]), f2bf(Ls[n][kb8 + 3]));
        w.z = pack2(f2bf(Ls[n][kb8 + 4]), f2bf(Ls[n][kb8 + 5]));
        w.w = pack2(f2bf(Ls[n][kb8 + 6]), f2bf(Ls[n][kb8 + 7]));
        size_t off = ((size_t)(kc * 24 + mat * 8 + f) * 64 + ln) * 8;
        *reinterpret_cast<uint4*>(&wt[off]) = w;
    }
}

// ---------------------------------------------------------------------------
// Fused QKV projection (unchanged from round 10 — passing, ~25us).
// ---------------------------------------------------------------------------
__global__ __launch_bounds__(512, 1)
void proj_kernel(const float* __restrict__ x, const unsigned short* __restrict__ wt,
                 const float* __restrict__ bq, const float* __restrict__ bk,
                 const float* __restrict__ bv,
                 unsigned short* __restrict__ qb, unsigned short* __restrict__ kb,
                 unsigned short* __restrict__ vtb)
{
    const int tid = threadIdx.x;
    const int lane = tid & 63, wv = tid >> 6;   // wv 0..7
    const int l15 = lane & 15, lg = lane >> 4;
    const int kof = lg * 8;

    const int rg = wv & 3;                      // row-group
    const int kh = wv >> 2;                     // k-half
    const int m0    = blockIdx.x * 64 + rg * 16;
    const int batch = m0 >> 12;
    const int t0    = m0 & (T_CTX - 1);
    const int kbeg  = kh * 512;

    f32x4 acc[3][4] = {};
    const float* xrow = &x[(size_t)(m0 + l15) * E_DIM + kof];
    const unsigned short* wlane = wt + (size_t)lane * 8;   // lane-folded

    float4 xa0 = *reinterpret_cast<const float4*>(xrow + kbeg);
    float4 xb0 = *reinterpret_cast<const float4*>(xrow + kbeg + 4);
    float4 xa1 = *reinterpret_cast<const float4*>(xrow + kbeg + 32);
    float4 xb1 = *reinterpret_cast<const float4*>(xrow + kbeg + 36);

    for (int k0 = kbeg; k0 < kbeg + 512; k0 += 32) {
        const int kn = (k0 + 64 < kbeg + 512) ? k0 + 64 : kbeg;
        float4 na = *reinterpret_cast<const float4*>(xrow + kn);
        float4 nb = *reinterpret_cast<const float4*>(xrow + kn + 4);

        const int fb = (k0 >> 6) * 24 + ((k0 >> 5) & 1);
        short8_t bf[12];
        #pragma unroll
        for (int mat = 0; mat < 3; ++mat)
            #pragma unroll
            for (int oc = 0; oc < 4; ++oc)
                bf[mat * 4 + oc] = *reinterpret_cast<const short8_t*>(
                    wlane + (size_t)(fb + mat * 8 + oc * 2) * 512);

        uint4 au;
        au.x = cvtpk(xa0.x, xa0.y); au.y = cvtpk(xa0.z, xa0.w);
        au.z = cvtpk(xb0.x, xb0.y); au.w = cvtpk(xb0.z, xb0.w);
        const short8_t a = __builtin_bit_cast(short8_t, au);

        #pragma unroll
        for (int mat = 0; mat < 3; ++mat)
            #pragma unroll
            for (int oc = 0; oc < 4; ++oc)
                acc[mat][oc] = __builtin_amdgcn_mfma_f32_16x16x32_bf16(
                    a, bf[mat * 4 + oc], acc[mat][oc], 0, 0, 0);

        xa0 = xa1; xb0 = xb1; xa1 = na; xb1 = nb;
    }

    __shared__ float Ms[4][64][49];              // 50 KB fp32 merge
    __shared__ unsigned short Stg[4][1024];      // 8 KB bf16 staging (NO alias)
    if (kh == 1) {
        #pragma unroll
        for (int mat = 0; mat < 3; ++mat)
            #pragma unroll
            for (int oc = 0; oc < 4; ++oc)
                #pragma unroll
                for (int r = 0; r < 4; ++r)
                    Ms[rg][lane][(mat * 4 + oc) * 4 + r] = acc[mat][oc][r];
    }
    __syncthreads();
    if (kh == 0) {
        #pragma unroll
        for (int mat = 0; mat < 3; ++mat)
            #pragma unroll
            for (int oc = 0; oc < 4; ++oc)
                #pragma unroll
                for (int r = 0; r < 4; ++r)
                    acc[mat][oc][r] += Ms[rg][lane][(mat * 4 + oc) * 4 + r];

        unsigned short* stage = &Stg[rg][0];

        #pragma unroll
        for (int mat = 0; mat < 2; ++mat) {
            const float* bias = mat ? bk : bq;
            const float sc = mat ? 1.0f : SCALE_Q;
            #pragma unroll
            for (int oc = 0; oc < 4; ++oc) {
                const float bb = bias[oc * 16 + l15];
                #pragma unroll
                for (int r = 0; r < 4; ++r)
                    stage[swz(lg * 4 + r, oc * 16 + l15)] =
                        f2bf((acc[mat][oc][r] + bb) * sc);
            }
            unsigned short* outg = mat ? kb : qb;
            const int row = lane >> 2, c = (lane & 3) * 16;
            uint4 w0 = *reinterpret_cast<const uint4*>(&stage[swz(row, c)]);
            uint4 w1 = *reinterpret_cast<const uint4*>(&stage[swz(row, c + 8)]);
            *reinterpret_cast<uint4*>(&outg[(size_t)(m0 + row) * H_DIM + c]) = w0;
            *reinterpret_cast<uint4*>(&outg[(size_t)(m0 + row) * H_DIM + c + 8]) = w1;
        }

        #pragma unroll
        for (int oc = 0; oc < 4; ++oc) {
            const float bb = bv[oc * 16 + l15];
            const int h = oc * 16 + l15;
            uint2 pw;
            pw.x = cvtpk(acc[2][oc][0] + bb, acc[2][oc][1] + bb);
            pw.y = cvtpk(acc[2][oc][2] + bb, acc[2][oc][3] + bb);
            *reinterpret_cast<uint2*>(&stage[h * 16 + lg * 4]) = pw;
        }
        const int h = lane;
        uint4 v0 = *reinterpret_cast<const uint4*>(&stage[h * 16]);
        uint4 v1 = *reinterpret_cast<const uint4*>(&stage[h * 16 + 8]);
        unsigned short* vrow = &vtb[((size_t)batch * H_DIM + h) * T_CTX + t0];
        *reinterpret_cast<uint4*>(&vrow[0]) = v0;
        *reinterpret_cast<uint4*>(&vrow[8]) = v1;
    }
}

// ---------------------------------------------------------------------------
// Causal flash attention, COMPLEMENTARY-PAIR schedule. 256 blocks x 512 thr;
// block b processes strip-unit rank b then rank 511-b (rank r -> strip
// 127-(r>>2), batch r&3) -> strips (127-p, p): per-wave serial tiles
// = ceil(nkv1/8)+ceil(nkv2/8) = 9 for EVERY block. Uniform per-CU work,
// direct output writes, no partials/fixup. 1 block/CU = 2 waves/SIMD ->
// VGPR budget free: V-hoist + 1-deep K prefetch (kfC/kfN named rotation).
// ---------------------------------------------------------------------------
__global__ __launch_bounds__(512)
void attn_kernel(const unsigned short* __restrict__ qg,
                 const unsigned short* __restrict__ kg,
                 const unsigned short* __restrict__ vt,
                 float* __restrict__ outp)
{
    const int tid  = threadIdx.x;
    const int lane = tid & 63, wv = tid >> 6;   // wv 0..7
    const int l15 = lane & 15, lg = lane >> 4;
    const int kof = lg * 8;

    __shared__ float smem[8448];                // Pt (32KB) ∪ merge (33KB)
    unsigned short* Pt = (unsigned short*)smem;
    const int pbase = wv * 2048;                // per-wave [32][64] bf16

    #pragma unroll 1
    for (int half = 0; half < 2; ++half) {
        const int r     = half ? (511 - (int)blockIdx.x) : (int)blockIdx.x;
        const int st    = 127 - (r >> 2);
        const int batch = r & 3;
        const int q0    = st * 32;
        const int nkv   = st / 2 + 1;           // 64-wide kv tiles
        const size_t rbase = (size_t)batch * T_CTX;
        const size_t vbase = (size_t)batch * H_DIM * T_CTX;

        __syncthreads();   // previous unit's merge reads done before Pt reuse

        short8_t qlo[2], qhi[2];
        #pragma unroll
        for (int hs = 0; hs < 2; ++hs) {
            qlo[hs] = *reinterpret_cast<const short8_t*>(
                &qg[(rbase + q0 + l15) * H_DIM + hs * 32 + kof]);
            qhi[hs] = *reinterpret_cast<const short8_t*>(
                &qg[(rbase + q0 + 16 + l15) * H_DIM + hs * 32 + kof]);
        }

        f32x4 olo[4] = {}, ohi[4] = {};
        float mlo = -1e30f, mhi = -1e30f, llo = 0.f, lhi = 0.f;

        // 1-deep K prefetch: kfC holds tile t's K fragments
        short8_t kfC[8];
        if (wv < nkv) {
            const unsigned short* kp = kg + (rbase + wv * 64 + l15) * H_DIM + kof;
            #pragma unroll
            for (int hs = 0; hs < 2; ++hs)
                #pragma unroll
                for (int ct = 0; ct < 4; ++ct)
                    kfC[hs * 4 + ct] = *reinterpret_cast<const short8_t*>(
                        kp + ct * 16 * H_DIM + hs * 32);
        }

        for (int t = wv; t < nkv; t += 8) {
            const int k0 = t * 64;
            const unsigned short* vp = vt + vbase + (size_t)l15 * T_CTX + k0 + kof;

            // V fragments issued EARLY (consumed after softmax)
            short8_t vf[8];
            #pragma unroll
            for (int oc = 0; oc < 4; ++oc)
                #pragma unroll
                for (int ks = 0; ks < 2; ++ks)
                    vf[oc * 2 + ks] = *reinterpret_cast<const short8_t*>(
                        vp + (size_t)(oc * 16) * T_CTX + ks * 32);

            // next tile's K issued EARLY (consumed next iteration)
            short8_t kfN[8];
            const bool havN = (t + 8 < nkv);
            if (havN) {
                const unsigned short* kp = kg + (rbase + (t + 8) * 64 + l15) * H_DIM + kof;
                #pragma unroll
                for (int hs = 0; hs < 2; ++hs)
                    #pragma unroll
                    for (int ct = 0; ct < 4; ++ct)
                        kfN[hs * 4 + ct] = *reinterpret_cast<const short8_t*>(
                            kp + ct * 16 * H_DIM + hs * 32);
            }

            f32x4 slo[4] = {}, shi[4] = {};
            #pragma unroll
            for (int hs = 0; hs < 2; ++hs)
                #pragma unroll
                for (int ct = 0; ct < 4; ++ct) {
                    slo[ct] = __builtin_amdgcn_mfma_f32_16x16x32_bf16(
                        kfC[hs * 4 + ct], qlo[hs], slo[ct], 0, 0, 0);
                    shi[ct] = __builtin_amdgcn_mfma_f32_16x16x32_bf16(
                        kfC[hs * 4 + ct], qhi[hs], shi[ct], 0, 0, 0);
                }

            if (t == nkv - 1) {   // only the strip's last tile crosses the diagonal
                #pragma unroll
                for (int ct = 0; ct < 4; ++ct)
                    #pragma unroll
                    for (int rr = 0; rr < 4; ++rr) {
                        const int kv = k0 + ct * 16 + lg * 4 + rr;
                        if (kv > q0 + l15)      slo[ct][rr] = -1e30f;
                        if (kv > q0 + 16 + l15) shi[ct][rr] = -1e30f;
                    }
            }

            float mxlo, mxhi;
            {
                float a = fmaxf(fmaxf(slo[0][0], slo[0][1]), fmaxf(slo[0][2], slo[0][3]));
                float b = fmaxf(fmaxf(slo[1][0], slo[1][1]), fmaxf(slo[1][2], slo[1][3]));
                float c = fmaxf(fmaxf(slo[2][0], slo[2][1]), fmaxf(slo[2][2], slo[2][3]));
                float d = fmaxf(fmaxf(slo[3][0], slo[3][1]), fmaxf(slo[3][2], slo[3][3]));
                mxlo = fmaxf(fmaxf(a, b), fmaxf(c, d));
                a = fmaxf(fmaxf(shi[0][0], shi[0][1]), fmaxf(shi[0][2], shi[0][3]));
                b = fmaxf(fmaxf(shi[1][0], shi[1][1]), fmaxf(shi[1][2], shi[1][3]));
                c = fmaxf(fmaxf(shi[2][0], shi[2][1]), fmaxf(shi[2][2], shi[2][3]));
                d = fmaxf(fmaxf(shi[3][0], shi[3][1]), fmaxf(shi[3][2], shi[3][3]));
                mxhi = fmaxf(fmaxf(a, b), fmaxf(c, d));
            }
            mxlo = fmaxf(mxlo, __shfl_xor(mxlo, 16));
            mxlo = fmaxf(mxlo, __shfl_xor(mxlo, 32));
            mxhi = fmaxf(mxhi, __shfl_xor(mxhi, 16));
            mxhi = fmaxf(mxhi, __shfl_xor(mxhi, 32));

            if (!__all((mxlo <= mlo + DEFER_THR) && (mxhi <= mhi + DEFER_THR))) {
                const float nmlo = fmaxf(mlo, mxlo), nmhi = fmaxf(mhi, mxhi);
                const float cflo = fexp2(mlo - nmlo), cfhi = fexp2(mhi - nmhi);
                llo *= cflo; lhi *= cfhi;
                mlo = nmlo; mhi = nmhi;
                #pragma unroll
                for (int rr = 0; rr < 4; ++rr) {
                    const float cl = __shfl(cflo, lg * 4 + rr);
                    const float ch = __shfl(cfhi, lg * 4 + rr);
                    #pragma unroll
                    for (int oc = 0; oc < 4; ++oc) { olo[oc][rr] *= cl; ohi[oc][rr] *= ch; }
                }
            }

            float rllo = 0.f, rlhi = 0.f;
            #pragma unroll
            for (int ct = 0; ct < 4; ++ct) {
                const float p0 = fexp2(slo[ct][0] - mlo), p1 = fexp2(slo[ct][1] - mlo);
                const float p2 = fexp2(slo[ct][2] - mlo), p3 = fexp2(slo[ct][3] - mlo);
                rllo += (p0 + p1) + (p2 + p3);
                uint2 pw; pw.x = cvtpk(p0, p1); pw.y = cvtpk(p2, p3);
                *reinterpret_cast<uint2*>(&Pt[pbase + swz(l15, ct * 16 + lg * 4)]) = pw;
                const float h0 = fexp2(shi[ct][0] - mhi), h1 = fexp2(shi[ct][1] - mhi);
                const float h2 = fexp2(shi[ct][2] - mhi), h3 = fexp2(shi[ct][3] - mhi);
                rlhi += (h0 + h1) + (h2 + h3);
                uint2 ph; ph.x = cvtpk(h0, h1); ph.y = cvtpk(h2, h3);
                *reinterpret_cast<uint2*>(&Pt[pbase + swz(16 + l15, ct * 16 + lg * 4)]) = ph;
            }
            rllo += __shfl_xor(rllo, 16); rllo += __shfl_xor(rllo, 32);
            rlhi += __shfl_xor(rlhi, 16); rlhi += __shfl_xor(rlhi, 32);
            llo += rllo; lhi += rlhi;

            #pragma unroll
            for (int ks = 0; ks < 2; ++ks) {
                const short8_t palo = *reinterpret_cast<const short8_t*>(
                    &Pt[pbase + swz(l15, ks * 32 + kof)]);
                const short8_t pahi = *reinterpret_cast<const short8_t*>(
                    &Pt[pbase + swz(16 + l15, ks * 32 + kof)]);
                #pragma unroll
                for (int oc = 0; oc < 4; ++oc) {
                    olo[oc] = __builtin_amdgcn_mfma_f32_16x16x32_bf16(
                        palo, vf[oc * 2 + ks], olo[oc], 0, 0, 0);
                    ohi[oc] = __builtin_amdgcn_mfma_f32_16x16x32_bf16(
                        pahi, vf[oc * 2 + ks], ohi[oc], 0, 0, 0);
                }
            }

            if (havN) {
                #pragma unroll
                for (int i = 0; i < 8; ++i) kfC[i] = kfN[i];
            }
        }

        // ---- two-phase merge + DIRECT output: ph 0 = lo rows, 1 = hi rows ----
        #pragma unroll 1
        for (int ph = 0; ph < 2; ++ph) {
            __syncthreads();
            #pragma unroll
            for (int oc = 0; oc < 4; ++oc)
                #pragma unroll
                for (int rr = 0; rr < 4; ++rr)
                    smem[wv * 1024 + (lg * 4 + rr) * 64 + oc * 16 + l15] =
                        ph ? ohi[oc][rr] : olo[oc][rr];
            if (lg == 0) {
                smem[8192 + wv * 16 + l15] = ph ? mhi : mlo;
                smem[8320 + wv * 16 + l15] = ph ? lhi : llo;
            }
            __syncthreads();
            const int row = tid >> 5;          // 0..15
            const int c2  = (tid & 31) * 2;
            float M = -1e30f;
            #pragma unroll
            for (int w = 0; w < 8; ++w) M = fmaxf(M, smem[8192 + w * 16 + row]);
            float L = 0.f, a0 = 0.f, a1 = 0.f;
            #pragma unroll
            for (int w = 0; w < 8; ++w) {
                const float e = fexp2(smem[8192 + w * 16 + row] - M);
                L += e * smem[8320 + w * 16 + row];
                a0 += e * smem[w * 1024 + row * 64 + c2];
                a1 += e * smem[w * 1024 + row * 64 + c2 + 1];
            }
            const float inv = 1.0f / L;
            float2 rr2; rr2.x = a0 * inv; rr2.y = a1 * inv;
            *reinterpret_cast<float2*>(
                &outp[(rbase + q0 + ph * 16 + row) * H_DIM + c2]) = rr2;
        }
    }
}

extern "C" void kernel_launch(void* const* d_in, const int* in_sizes, int n_in,
                              void* d_out, int out_size, void* d_ws, size_t ws_size,
                              hipStream_t stream) {
    const float* x  = (const float*)d_in[0];
    const float* Wq = (const float*)d_in[1];
    const float* bq = (const float*)d_in[2];
    const float* Wk = (const float*)d_in[3];
    const float* bk = (const float*)d_in[4];
    const float* Wv = (const float*)d_in[5];
    const float* bv = (const float*)d_in[6];
    float* out = (float*)d_out;

    // ws (ushort): Wt[3*64*1024] | q[16384*64] | k[16384*64] | vt[4*64*4096]
    unsigned short* wt  = (unsigned short*)d_ws;
    unsigned short* qb  = wt + 3 * H_DIM * E_DIM;
    unsigned short* kb  = qb + (size_t)M_ROWS * H_DIM;
    unsigned short* vtb = kb + (size_t)M_ROWS * H_DIM;

    prep_weights<<<dim3(E_DIM / 64, 3), 256, 0, stream>>>(Wq, Wk, Wv, wt);
    proj_kernel<<<dim3(M_ROWS / 64), 512, 0, stream>>>(x, wt, bq, bk, bv, qb, kb, vtb);
    attn_kernel<<<dim3(256), 512, 0, stream>>>(qb, kb, vtb, out);
}

// Round 14
// 60.195 us; speedup vs baseline: 1.8092x; 1.1633x over previous
//
#include <hip/hip_runtime.h>

typedef __attribute__((ext_vector_type(8))) short short8_t;
typedef __attribute__((ext_vector_type(4))) float f32x4;

namespace {
constexpr int T_CTX  = 4096;
constexpr int E_DIM  = 1024;
constexpr int H_DIM  = 64;
constexpr int B_SZ   = 4;
constexpr int M_ROWS = B_SZ * T_CTX; // 16384
// 1/sqrt(H) * log2(e): S lands in log2 domain -> softmax via exp2
constexpr float SCALE_Q = 0.125f * 1.4426950408889634f;
constexpr float DEFER_THR = 8.0f;    // log2 units; P bounded by 2^8
}

__device__ __forceinline__ unsigned short f2bf(float f) {
    unsigned u = __builtin_bit_cast(unsigned, f);
    u += 0x7fffu + ((u >> 16) & 1u);          // RNE
    return (unsigned short)(u >> 16);
}
__device__ __forceinline__ unsigned pack2(unsigned short lo, unsigned short hi) {
    return (unsigned)lo | ((unsigned)hi << 16);
}
__device__ __forceinline__ unsigned cvtpk(float lo, float hi) {
    unsigned r;
    asm("v_cvt_pk_bf16_f32 %0, %1, %2" : "=v"(r) : "v"(lo), "v"(hi));
    return r;
}
__device__ __forceinline__ float fexp2(float x) {   // guaranteed v_exp_f32
    float r;
    asm("v_exp_f32 %0, %1" : "=v"(r) : "v"(x));
    return r;
}
// swizzled ushort index into a row-major [rows][64] bf16 LDS tile
__device__ __forceinline__ int swz(int row, int col) {
    return row * 64 + (col ^ ((row & 7) << 3));
}

// ---------------------------------------------------------------------------
// Weight prep: W[1024][64] fp32 -> FRAGMENT-MAJOR bf16 layout (1KB streams).
// ---------------------------------------------------------------------------
__global__ __launch_bounds__(256)
void prep_weights(const float* __restrict__ Wq, const float* __restrict__ Wk,
                  const float* __restrict__ Wv, unsigned short* __restrict__ wt)
{
    const int mat = blockIdx.y;
    const int kc  = blockIdx.x;
    const float* W = (mat == 0) ? Wq : (mat == 1) ? Wk : Wv;
    __shared__ float Ls[64][65];   // Ls[n][k_local]
    const int tid = threadIdx.x;
    const int kb = kc * 64;
    #pragma unroll
    for (int j = 0; j < 4; ++j) {
        int p = j * 256 + tid;
        int kr = p >> 4, c4 = (p & 15) * 4;
        float4 w4 = *reinterpret_cast<const float4*>(&W[(size_t)(kb + kr) * H_DIM + c4]);
        Ls[c4 + 0][kr] = w4.x; Ls[c4 + 1][kr] = w4.y;
        Ls[c4 + 2][kr] = w4.z; Ls[c4 + 3][kr] = w4.w;
    }
    __syncthreads();
    #pragma unroll
    for (int j = 0; j < 2; ++j) {
        int p = j * 256 + tid;       // 0..511
        int f  = p >> 6;             // 0..7 = oc*2 + hs
        int ln = p & 63;
        int n   = (f >> 1) * 16 + (ln & 15);
        int kb8 = (f & 1) * 32 + (ln >> 4) * 8;
        uint4 w;
        w.x = pack2(f2bf(Ls[n][kb8 + 0]), f2bf(Ls[n][kb8 + 1]));
        w.y = pack2(f2bf(Ls[n][kb8 + 2]), f2bf(Ls[n][kb8 + 3]));
        w.z = pack2(f2bf(Ls[n][kb8 + 4]), f2bf(Ls[n][kb8 + 5]));
        w.w = pack2(f2bf(Ls[n][kb8 + 6]), f2bf(Ls[n][kb8 + 7]));
        size_t off = ((size_t)(kc * 24 + mat * 8 + f) * 64 + ln) * 8;
        *reinterpret_cast<uint4*>(&wt[off]) = w;
    }
}

// ---------------------------------------------------------------------------
// Fused QKV projection. Main loop unchanged (fragment-major wt, 2-deep x
// prefetch). NEW epilogue: emits K and V in MFMA-FRAGMENT-MAJOR layout so
// attn's loads are contiguous 1KB wave-streams (TA-coalesced) instead of
// 16-line gathers:
//   kfb[((batch*64+t)*8 + hs*4+ct)*512 + lane*8] = K[t*64+ct*16+(lane&15)]
//                                                   [hs*32+(lane>>4)*8 ..]
//   vfb[((batch*64+t)*8 + oc*2+ks)*512 + lane*8] = V[t*64+ks*32+(lane>>4)*8..]
//                                                   [oc*16+(lane&15)]  (kv fast)
// V needs a cross-rg transpose -> block-wide Vst[64 h][64 t] LDS stage.
// ---------------------------------------------------------------------------
__global__ __launch_bounds__(512, 1)
void proj_kernel(const float* __restrict__ x, const unsigned short* __restrict__ wt,
                 const float* __restrict__ bq, const float* __restrict__ bk,
                 const float* __restrict__ bv,
                 unsigned short* __restrict__ qb, unsigned short* __restrict__ kfb,
                 unsigned short* __restrict__ vfb)
{
    const int tid = threadIdx.x;
    const int lane = tid & 63, wv = tid >> 6;   // wv 0..7
    const int l15 = lane & 15, lg = lane >> 4;
    const int kof = lg * 8;

    const int rg = wv & 3;                      // row-group (= ct quarter)
    const int kh = wv >> 2;                     // k-half
    const int m0    = blockIdx.x * 64 + rg * 16;
    const int batch = blockIdx.x >> 6;          // 64 tiles per batch
    const int tt    = blockIdx.x & 63;          // tile index within batch
    const int kbeg  = kh * 512;

    f32x4 acc[3][4] = {};
    const float* xrow = &x[(size_t)(m0 + l15) * E_DIM + kof];
    const unsigned short* wlane = wt + (size_t)lane * 8;   // lane-folded

    float4 xa0 = *reinterpret_cast<const float4*>(xrow + kbeg);
    float4 xb0 = *reinterpret_cast<const float4*>(xrow + kbeg + 4);
    float4 xa1 = *reinterpret_cast<const float4*>(xrow + kbeg + 32);
    float4 xb1 = *reinterpret_cast<const float4*>(xrow + kbeg + 36);

    for (int k0 = kbeg; k0 < kbeg + 512; k0 += 32) {
        const int kn = (k0 + 64 < kbeg + 512) ? k0 + 64 : kbeg;
        float4 na = *reinterpret_cast<const float4*>(xrow + kn);
        float4 nb = *reinterpret_cast<const float4*>(xrow + kn + 4);

        const int fb = (k0 >> 6) * 24 + ((k0 >> 5) & 1);
        short8_t bf[12];
        #pragma unroll
        for (int mat = 0; mat < 3; ++mat)
            #pragma unroll
            for (int oc = 0; oc < 4; ++oc)
                bf[mat * 4 + oc] = *reinterpret_cast<const short8_t*>(
                    wlane + (size_t)(fb + mat * 8 + oc * 2) * 512);

        uint4 au;
        au.x = cvtpk(xa0.x, xa0.y); au.y = cvtpk(xa0.z, xa0.w);
        au.z = cvtpk(xb0.x, xb0.y); au.w = cvtpk(xb0.z, xb0.w);
        const short8_t a = __builtin_bit_cast(short8_t, au);

        #pragma unroll
        for (int mat = 0; mat < 3; ++mat)
            #pragma unroll
            for (int oc = 0; oc < 4; ++oc)
                acc[mat][oc] = __builtin_amdgcn_mfma_f32_16x16x32_bf16(
                    a, bf[mat * 4 + oc], acc[mat][oc], 0, 0, 0);

        xa0 = xa1; xb0 = xb1; xa1 = na; xb1 = nb;
    }

    // ---- k-half merge, TWO passes (fits 50KB LDS with Vst) ----
    __shared__ float Ms[4][64][33];              // 33.8 KB fp32 merge
    __shared__ unsigned short Stg[4][1024];      // 8 KB bf16 staging (r8 lesson)
    __shared__ unsigned short Vst[64 * 64];      // 8 KB block-wide V^T stage
    if (kh == 1) {
        #pragma unroll
        for (int mat = 0; mat < 2; ++mat)
            #pragma unroll
            for (int oc = 0; oc < 4; ++oc)
                #pragma unroll
                for (int r = 0; r < 4; ++r)
                    Ms[rg][lane][(mat * 4 + oc) * 4 + r] = acc[mat][oc][r];
    }
    __syncthreads();
    if (kh == 0) {
        #pragma unroll
        for (int mat = 0; mat < 2; ++mat)
            #pragma unroll
            for (int oc = 0; oc < 4; ++oc)
                #pragma unroll
                for (int r = 0; r < 4; ++r)
                    acc[mat][oc][r] += Ms[rg][lane][(mat * 4 + oc) * 4 + r];
    }
    __syncthreads();
    if (kh == 1) {
        #pragma unroll
        for (int oc = 0; oc < 4; ++oc)
            #pragma unroll
            for (int r = 0; r < 4; ++r)
                Ms[rg][lane][oc * 4 + r] = acc[2][oc][r];
    }
    __syncthreads();
    if (kh == 0) {
        #pragma unroll
        for (int oc = 0; oc < 4; ++oc)
            #pragma unroll
            for (int r = 0; r < 4; ++r)
                acc[2][oc][r] += Ms[rg][lane][oc * 4 + r];

        unsigned short* stage = &Stg[rg][0];

        // ---- q: stage swizzled -> coalesced row-major write ----
        #pragma unroll
        for (int oc = 0; oc < 4; ++oc) {
            const float bb = bq[oc * 16 + l15];
            #pragma unroll
            for (int r = 0; r < 4; ++r)
                stage[swz(lg * 4 + r, oc * 16 + l15)] =
                    f2bf((acc[0][oc][r] + bb) * SCALE_Q);
        }
        {
            const int row = lane >> 2, c = (lane & 3) * 16;
            uint4 w0 = *reinterpret_cast<const uint4*>(&stage[swz(row, c)]);
            uint4 w1 = *reinterpret_cast<const uint4*>(&stage[swz(row, c + 8)]);
            *reinterpret_cast<uint4*>(&qb[(size_t)(m0 + row) * H_DIM + c]) = w0;
            *reinterpret_cast<uint4*>(&qb[(size_t)(m0 + row) * H_DIM + c + 8]) = w1;
        }

        // ---- k: stage swizzled -> 2 FRAGMENT writes (this rg == ct) ----
        #pragma unroll
        for (int oc = 0; oc < 4; ++oc) {
            const float bb = bk[oc * 16 + l15];
            #pragma unroll
            for (int r = 0; r < 4; ++r)
                stage[swz(lg * 4 + r, oc * 16 + l15)] =
                    f2bf(acc[1][oc][r] + bb);
        }
        #pragma unroll
        for (int hs = 0; hs < 2; ++hs) {
            uint4 w = *reinterpret_cast<const uint4*>(&stage[swz(l15, hs * 32 + kof)]);
            *reinterpret_cast<uint4*>(
                &kfb[(((size_t)batch * 64 + tt) * 8 + hs * 4 + rg) * 512 + lane * 8]) = w;
        }

        // ---- v: write V^T slice into block-wide Vst[h][t_local] ----
        #pragma unroll
        for (int oc = 0; oc < 4; ++oc) {
            const float bb = bv[oc * 16 + l15];
            const int h = oc * 16 + l15;
            uint2 pw;
            pw.x = cvtpk(acc[2][oc][0] + bb, acc[2][oc][1] + bb);
            pw.y = cvtpk(acc[2][oc][2] + bb, acc[2][oc][3] + bb);
            const int c = (rg * 16 + lg * 4) ^ ((h & 7) << 3);
            *reinterpret_cast<uint2*>(&Vst[h * 64 + c]) = pw;
        }
    }
    __syncthreads();   // Vst complete

    // ---- all 8 waves: emit one V fragment each (g = wv = oc*2+ks) ----
    {
        const int g = wv;
        const int hrow = (g >> 1) * 16 + l15;
        const int c = ((g & 1) * 32 + kof) ^ ((hrow & 7) << 3);
        uint4 w = *reinterpret_cast<const uint4*>(&Vst[hrow * 64 + c]);
        *reinterpret_cast<uint4*>(
            &vfb[(((size_t)batch * 64 + tt) * 8 + g) * 512 + lane * 8]) = w;
    }
}

// ---------------------------------------------------------------------------
// Causal flash attention, COMPLEMENTARY-PAIR schedule (r13 structure),
// K/V read from FRAGMENT-MAJOR buffers: every load = contiguous 1KB
// wave-stream (16 consecutive lines) instead of a 16-line gather.
// ---------------------------------------------------------------------------
__global__ __launch_bounds__(512)
void attn_kernel(const unsigned short* __restrict__ qg,
                 const unsigned short* __restrict__ kfb,
                 const unsigned short* __restrict__ vfb,
                 float* __restrict__ outp)
{
    const int tid  = threadIdx.x;
    const int lane = tid & 63, wv = tid >> 6;   // wv 0..7
    const int l15 = lane & 15, lg = lane >> 4;
    const int kof = lg * 8;

    __shared__ float smem[8448];                // Pt (32KB) ∪ merge (33KB)
    unsigned short* Pt = (unsigned short*)smem;
    const int pbase = wv * 2048;                // per-wave [32][64] bf16

    #pragma unroll 1
    for (int half = 0; half < 2; ++half) {
        const int r     = half ? (511 - (int)blockIdx.x) : (int)blockIdx.x;
        const int st    = 127 - (r >> 2);
        const int batch = r & 3;
        const int q0    = st * 32;
        const int nkv   = st / 2 + 1;           // 64-wide kv tiles
        const size_t rbase = (size_t)batch * T_CTX;
        const size_t fbase = (size_t)(batch * 64) * 8 * 512 + (size_t)lane * 8;

        __syncthreads();   // previous unit's merge reads done before Pt reuse

        short8_t qlo[2], qhi[2];
        #pragma unroll
        for (int hs = 0; hs < 2; ++hs) {
            qlo[hs] = *reinterpret_cast<const short8_t*>(
                &qg[(rbase + q0 + l15) * H_DIM + hs * 32 + kof]);
            qhi[hs] = *reinterpret_cast<const short8_t*>(
                &qg[(rbase + q0 + 16 + l15) * H_DIM + hs * 32 + kof]);
        }

        f32x4 olo[4] = {}, ohi[4] = {};
        float mlo = -1e30f, mhi = -1e30f, llo = 0.f, lhi = 0.f;

        // 1-deep K prefetch: kfC holds tile t's K fragments (contiguous loads)
        short8_t kfC[8];
        if (wv < nkv) {
            const unsigned short* kp = kfb + fbase + (size_t)wv * 8 * 512;
            #pragma unroll
            for (int i = 0; i < 8; ++i)
                kfC[i] = *reinterpret_cast<const short8_t*>(kp + i * 512);
        }

        for (int t = wv; t < nkv; t += 8) {
            const int k0 = t * 64;

            // V fragments issued EARLY (consumed after softmax)
            const unsigned short* vp = vfb + fbase + (size_t)t * 8 * 512;
            short8_t vf[8];
            #pragma unroll
            for (int g = 0; g < 8; ++g)
                vf[g] = *reinterpret_cast<const short8_t*>(vp + g * 512);

            // next tile's K issued EARLY (consumed next iteration)
            short8_t kfN[8];
            const bool havN = (t + 8 < nkv);
            if (havN) {
                const unsigned short* kp = kfb + fbase + (size_t)(t + 8) * 8 * 512;
                #pragma unroll
                for (int i = 0; i < 8; ++i)
                    kfN[i] = *reinterpret_cast<const short8_t*>(kp + i * 512);
            }

            f32x4 slo[4] = {}, shi[4] = {};
            #pragma unroll
            for (int hs = 0; hs < 2; ++hs)
                #pragma unroll
                for (int ct = 0; ct < 4; ++ct) {
                    slo[ct] = __builtin_amdgcn_mfma_f32_16x16x32_bf16(
                        kfC[hs * 4 + ct], qlo[hs], slo[ct], 0, 0, 0);
                    shi[ct] = __builtin_amdgcn_mfma_f32_16x16x32_bf16(
                        kfC[hs * 4 + ct], qhi[hs], shi[ct], 0, 0, 0);
                }

            if (t == nkv - 1) {   // only the strip's last tile crosses the diagonal
                #pragma unroll
                for (int ct = 0; ct < 4; ++ct)
                    #pragma unroll
                    for (int rr = 0; rr < 4; ++rr) {
                        const int kv = k0 + ct * 16 + lg * 4 + rr;
                        if (kv > q0 + l15)      slo[ct][rr] = -1e30f;
                        if (kv > q0 + 16 + l15) shi[ct][rr] = -1e30f;
                    }
            }

            float mxlo, mxhi;
            {
                float a = fmaxf(fmaxf(slo[0][0], slo[0][1]), fmaxf(slo[0][2], slo[0][3]));
                float b = fmaxf(fmaxf(slo[1][0], slo[1][1]), fmaxf(slo[1][2], slo[1][3]));
                float c = fmaxf(fmaxf(slo[2][0], slo[2][1]), fmaxf(slo[2][2], slo[2][3]));
                float d = fmaxf(fmaxf(slo[3][0], slo[3][1]), fmaxf(slo[3][2], slo[3][3]));
                mxlo = fmaxf(fmaxf(a, b), fmaxf(c, d));
                a = fmaxf(fmaxf(shi[0][0], shi[0][1]), fmaxf(shi[0][2], shi[0][3]));
                b = fmaxf(fmaxf(shi[1][0], shi[1][1]), fmaxf(shi[1][2], shi[1][3]));
                c = fmaxf(fmaxf(shi[2][0], shi[2][1]), fmaxf(shi[2][2], shi[2][3]));
                d = fmaxf(fmaxf(shi[3][0], shi[3][1]), fmaxf(shi[3][2], shi[3][3]));
                mxhi = fmaxf(fmaxf(a, b), fmaxf(c, d));
            }
            mxlo = fmaxf(mxlo, __shfl_xor(mxlo, 16));
            mxlo = fmaxf(mxlo, __shfl_xor(mxlo, 32));
            mxhi = fmaxf(mxhi, __shfl_xor(mxhi, 16));
            mxhi = fmaxf(mxhi, __shfl_xor(mxhi, 32));

            if (!__all((mxlo <= mlo + DEFER_THR) && (mxhi <= mhi + DEFER_THR))) {
                const float nmlo = fmaxf(mlo, mxlo), nmhi = fmaxf(mhi, mxhi);
                const float cflo = fexp2(mlo - nmlo), cfhi = fexp2(mhi - nmhi);
                llo *= cflo; lhi *= cfhi;
                mlo = nmlo; mhi = nmhi;
                #pragma unroll
                for (int rr = 0; rr < 4; ++rr) {
                    const float cl = __shfl(cflo, lg * 4 + rr);
                    const float ch = __shfl(cfhi, lg * 4 + rr);
                    #pragma unroll
                    for (int oc = 0; oc < 4; ++oc) { olo[oc][rr] *= cl; ohi[oc][rr] *= ch; }
                }
            }

            float rllo = 0.f, rlhi = 0.f;
            #pragma unroll
            for (int ct = 0; ct < 4; ++ct) {
                const float p0 = fexp2(slo[ct][0] - mlo), p1 = fexp2(slo[ct][1] - mlo);
                const float p2 = fexp2(slo[ct][2] - mlo), p3 = fexp2(slo[ct][3] - mlo);
                rllo += (p0 + p1) + (p2 + p3);
                uint2 pw; pw.x = cvtpk(p0, p1); pw.y = cvtpk(p2, p3);
                *reinterpret_cast<uint2*>(&Pt[pbase + swz(l15, ct * 16 + lg * 4)]) = pw;
                const float h0 = fexp2(shi[ct][0] - mhi), h1 = fexp2(shi[ct][1] - mhi);
                const float h2 = fexp2(shi[ct][2] - mhi), h3 = fexp2(shi[ct][3] - mhi);
                rlhi += (h0 + h1) + (h2 + h3);
                uint2 ph; ph.x = cvtpk(h0, h1); ph.y = cvtpk(h2, h3);
                *reinterpret_cast<uint2*>(&Pt[pbase + swz(16 + l15, ct * 16 + lg * 4)]) = ph;
            }
            rllo += __shfl_xor(rllo, 16); rllo += __shfl_xor(rllo, 32);
            rlhi += __shfl_xor(rlhi, 16); rlhi += __shfl_xor(rlhi, 32);
            llo += rllo; lhi += rlhi;

            #pragma unroll
            for (int ks = 0; ks < 2; ++ks) {
                const short8_t palo = *reinterpret_cast<const short8_t*>(
                    &Pt[pbase + swz(l15, ks * 32 + kof)]);
                const short8_t pahi = *reinterpret_cast<const short8_t*>(
                    &Pt[pbase + swz(16 + l15, ks * 32 + kof)]);
                #pragma unroll
                for (int oc = 0; oc < 4; ++oc) {
                    olo[oc] = __builtin_amdgcn_mfma_f32_16x16x32_bf16(
                        palo, vf[oc * 2 + ks], olo[oc], 0, 0, 0);
                    ohi[oc] = __builtin_amdgcn_mfma_f32_16x16x32_bf16(
                        pahi, vf[oc * 2 + ks], ohi[oc], 0, 0, 0);
                }
            }

            if (havN) {
                #pragma unroll
                for (int i = 0; i < 8; ++i) kfC[i] = kfN[i];
            }
        }

        // ---- two-phase merge + DIRECT output: ph 0 = lo rows, 1 = hi rows ----
        #pragma unroll 1
        for (int ph = 0; ph < 2; ++ph) {
            __syncthreads();
            #pragma unroll
            for (int oc = 0; oc < 4; ++oc)
                #pragma unroll
                for (int rr = 0; rr < 4; ++rr)
                    smem[wv * 1024 + (lg * 4 + rr) * 64 + oc * 16 + l15] =
                        ph ? ohi[oc][rr] : olo[oc][rr];
            if (lg == 0) {
                smem[8192 + wv * 16 + l15] = ph ? mhi : mlo;
                smem[8320 + wv * 16 + l15] = ph ? lhi : llo;
            }
            __syncthreads();
            const int row = tid >> 5;          // 0..15
            const int c2  = (tid & 31) * 2;
            float M = -1e30f;
            #pragma unroll
            for (int w = 0; w < 8; ++w) M = fmaxf(M, smem[8192 + w * 16 + row]);
            float L = 0.f, a0 = 0.f, a1 = 0.f;
            #pragma unroll
            for (int w = 0; w < 8; ++w) {
                const float e = fexp2(smem[8192 + w * 16 + row] - M);
                L += e * smem[8320 + w * 16 + row];
                a0 += e * smem[w * 1024 + row * 64 + c2];
                a1 += e * smem[w * 1024 + row * 64 + c2 + 1];
            }
            const float inv = 1.0f / L;
            float2 rr2; rr2.x = a0 * inv; rr2.y = a1 * inv;
            *reinterpret_cast<float2*>(
                &outp[(rbase + q0 + ph * 16 + row) * H_DIM + c2]) = rr2;
        }
    }
}

extern "C" void kernel_launch(void* const* d_in, const int* in_sizes, int n_in,
                              void* d_out, int out_size, void* d_ws, size_t ws_size,
                              hipStream_t stream) {
    const float* x  = (const float*)d_in[0];
    const float* Wq = (const float*)d_in[1];
    const float* bq = (const float*)d_in[2];
    const float* Wk = (const float*)d_in[3];
    const float* bk = (const float*)d_in[4];
    const float* Wv = (const float*)d_in[5];
    const float* bv = (const float*)d_in[6];
    float* out = (float*)d_out;

    // ws (ushort): Wt[3*64*1024] | q[16384*64] | kfb[4*64*8*512] | vfb[same]
    unsigned short* wt  = (unsigned short*)d_ws;
    unsigned short* qb  = wt + 3 * H_DIM * E_DIM;
    unsigned short* kfb = qb + (size_t)M_ROWS * H_DIM;
    unsigned short* vfb = kfb + (size_t)M_ROWS * H_DIM;

    prep_weights<<<dim3(E_DIM / 64, 3), 256, 0, stream>>>(Wq, Wk, Wv, wt);
    proj_kernel<<<dim3(M_ROWS / 64), 512, 0, stream>>>(x, wt, bq, bk, bv, qb, kfb, vfb);
    attn_kernel<<<dim3(256), 512, 0, stream>>>(qb, kfb, vfb, out);
}

// Round 15
// 56.239 us; speedup vs baseline: 1.9365x; 1.0704x over previous
//
#include <hip/hip_runtime.h>

typedef __attribute__((ext_vector_type(8))) short short8_t;
typedef __attribute__((ext_vector_type(4))) float f32x4;

namespace {
constexpr int T_CTX  = 4096;
constexpr int E_DIM  = 1024;
constexpr int H_DIM  = 64;
constexpr int B_SZ   = 4;
constexpr int M_ROWS = B_SZ * T_CTX; // 16384
// 1/sqrt(H) * log2(e): S lands in log2 domain -> softmax via exp2
constexpr float SCALE_Q = 0.125f * 1.4426950408889634f;
constexpr float DEFER_THR = 8.0f;    // log2 units; P bounded by 2^8
}

__device__ __forceinline__ unsigned short f2bf(float f) {
    unsigned u = __builtin_bit_cast(unsigned, f);
    u += 0x7fffu + ((u >> 16) & 1u);          // RNE
    return (unsigned short)(u >> 16);
}
__device__ __forceinline__ unsigned pack2(unsigned short lo, unsigned short hi) {
    return (unsigned)lo | ((unsigned)hi << 16);
}
__device__ __forceinline__ unsigned cvtpk(float lo, float hi) {
    unsigned r;
    asm("v_cvt_pk_bf16_f32 %0, %1, %2" : "=v"(r) : "v"(lo), "v"(hi));
    return r;
}
__device__ __forceinline__ float fexp2(float x) {   // guaranteed v_exp_f32
    float r;
    asm("v_exp_f32 %0, %1" : "=v"(r) : "v"(x));
    return r;
}
// swizzled ushort index into a row-major [rows][64] bf16 LDS tile
__device__ __forceinline__ int swz(int row, int col) {
    return row * 64 + (col ^ ((row & 7) << 3));
}

// ---------------------------------------------------------------------------
// Weight prep: W[1024][64] fp32 -> FRAGMENT-MAJOR bf16 layout (1KB streams).
// ---------------------------------------------------------------------------
__global__ __launch_bounds__(256)
void prep_weights(const float* __restrict__ Wq, const float* __restrict__ Wk,
                  const float* __restrict__ Wv, unsigned short* __restrict__ wt)
{
    const int mat = blockIdx.y;
    const int kc  = blockIdx.x;
    const float* W = (mat == 0) ? Wq : (mat == 1) ? Wk : Wv;
    __shared__ float Ls[64][65];   // Ls[n][k_local]
    const int tid = threadIdx.x;
    const int kb = kc * 64;
    #pragma unroll
    for (int j = 0; j < 4; ++j) {
        int p = j * 256 + tid;
        int kr = p >> 4, c4 = (p & 15) * 4;
        float4 w4 = *reinterpret_cast<const float4*>(&W[(size_t)(kb + kr) * H_DIM + c4]);
        Ls[c4 + 0][kr] = w4.x; Ls[c4 + 1][kr] = w4.y;
        Ls[c4 + 2][kr] = w4.z; Ls[c4 + 3][kr] = w4.w;
    }
    __syncthreads();
    #pragma unroll
    for (int j = 0; j < 2; ++j) {
        int p = j * 256 + tid;       // 0..511
        int f  = p >> 6;             // 0..7 = oc*2 + hs
        int ln = p & 63;
        int n   = (f >> 1) * 16 + (ln & 15);
        int kb8 = (f & 1) * 32 + (ln >> 4) * 8;
        uint4 w;
        w.x = pack2(f2bf(Ls[n][kb8 + 0]), f2bf(Ls[n][kb8 + 1]));
        w.y = pack2(f2bf(Ls[n][kb8 + 2]), f2bf(Ls[n][kb8 + 3]));
        w.z = pack2(f2bf(Ls[n][kb8 + 4]), f2bf(Ls[n][kb8 + 5]));
        w.w = pack2(f2bf(Ls[n][kb8 + 6]), f2bf(Ls[n][kb8 + 7]));
        size_t off = ((size_t)(kc * 24 + mat * 8 + f) * 64 + ln) * 8;
        *reinterpret_cast<uint4*>(&wt[off]) = w;
    }
}

// ---------------------------------------------------------------------------
// Fused QKV projection — EXACT r13 version (known-fast codegen, VGPR~128):
// fragment-major wt loads, 2-deep x prefetch, one-pass 50KB merge, dedicated
// Stg staging; emits q/k ROW-MAJOR and v transposed vt[b][h][t]. The
// fragment-major K/V repack happens in repack_kv (r14's in-proj epilogue
// flipped the register allocator to VGPR=64 and serialized the loads).
// ---------------------------------------------------------------------------
__global__ __launch_bounds__(512, 1)
void proj_kernel(const float* __restrict__ x, const unsigned short* __restrict__ wt,
                 const float* __restrict__ bq, const float* __restrict__ bk,
                 const float* __restrict__ bv,
                 unsigned short* __restrict__ qb, unsigned short* __restrict__ kb,
                 unsigned short* __restrict__ vtb)
{
    const int tid = threadIdx.x;
    const int lane = tid & 63, wv = tid >> 6;   // wv 0..7
    const int l15 = lane & 15, lg = lane >> 4;
    const int kof = lg * 8;

    const int rg = wv & 3;                      // row-group
    const int kh = wv >> 2;                     // k-half
    const int m0    = blockIdx.x * 64 + rg * 16;
    const int batch = m0 >> 12;
    const int t0    = m0 & (T_CTX - 1);
    const int kbeg  = kh * 512;

    f32x4 acc[3][4] = {};
    const float* xrow = &x[(size_t)(m0 + l15) * E_DIM + kof];
    const unsigned short* wlane = wt + (size_t)lane * 8;   // lane-folded

    float4 xa0 = *reinterpret_cast<const float4*>(xrow + kbeg);
    float4 xb0 = *reinterpret_cast<const float4*>(xrow + kbeg + 4);
    float4 xa1 = *reinterpret_cast<const float4*>(xrow + kbeg + 32);
    float4 xb1 = *reinterpret_cast<const float4*>(xrow + kbeg + 36);

    for (int k0 = kbeg; k0 < kbeg + 512; k0 += 32) {
        const int kn = (k0 + 64 < kbeg + 512) ? k0 + 64 : kbeg;
        float4 na = *reinterpret_cast<const float4*>(xrow + kn);
        float4 nb = *reinterpret_cast<const float4*>(xrow + kn + 4);

        const int fb = (k0 >> 6) * 24 + ((k0 >> 5) & 1);
        short8_t bf[12];
        #pragma unroll
        for (int mat = 0; mat < 3; ++mat)
            #pragma unroll
            for (int oc = 0; oc < 4; ++oc)
                bf[mat * 4 + oc] = *reinterpret_cast<const short8_t*>(
                    wlane + (size_t)(fb + mat * 8 + oc * 2) * 512);

        uint4 au;
        au.x = cvtpk(xa0.x, xa0.y); au.y = cvtpk(xa0.z, xa0.w);
        au.z = cvtpk(xb0.x, xb0.y); au.w = cvtpk(xb0.z, xb0.w);
        const short8_t a = __builtin_bit_cast(short8_t, au);

        #pragma unroll
        for (int mat = 0; mat < 3; ++mat)
            #pragma unroll
            for (int oc = 0; oc < 4; ++oc)
                acc[mat][oc] = __builtin_amdgcn_mfma_f32_16x16x32_bf16(
                    a, bf[mat * 4 + oc], acc[mat][oc], 0, 0, 0);

        xa0 = xa1; xb0 = xb1; xa1 = na; xb1 = nb;
    }

    __shared__ float Ms[4][64][49];              // 50 KB fp32 merge
    __shared__ unsigned short Stg[4][1024];      // 8 KB bf16 staging (NO alias)
    if (kh == 1) {
        #pragma unroll
        for (int mat = 0; mat < 3; ++mat)
            #pragma unroll
            for (int oc = 0; oc < 4; ++oc)
                #pragma unroll
                for (int r = 0; r < 4; ++r)
                    Ms[rg][lane][(mat * 4 + oc) * 4 + r] = acc[mat][oc][r];
    }
    __syncthreads();
    if (kh == 0) {
        #pragma unroll
        for (int mat = 0; mat < 3; ++mat)
            #pragma unroll
            for (int oc = 0; oc < 4; ++oc)
                #pragma unroll
                for (int r = 0; r < 4; ++r)
                    acc[mat][oc][r] += Ms[rg][lane][(mat * 4 + oc) * 4 + r];

        unsigned short* stage = &Stg[rg][0];

        #pragma unroll
        for (int mat = 0; mat < 2; ++mat) {
            const float* bias = mat ? bk : bq;
            const float sc = mat ? 1.0f : SCALE_Q;
            #pragma unroll
            for (int oc = 0; oc < 4; ++oc) {
                const float bb = bias[oc * 16 + l15];
                #pragma unroll
                for (int r = 0; r < 4; ++r)
                    stage[swz(lg * 4 + r, oc * 16 + l15)] =
                        f2bf((acc[mat][oc][r] + bb) * sc);
            }
            unsigned short* outg = mat ? kb : qb;
            const int row = lane >> 2, c = (lane & 3) * 16;
            uint4 w0 = *reinterpret_cast<const uint4*>(&stage[swz(row, c)]);
            uint4 w1 = *reinterpret_cast<const uint4*>(&stage[swz(row, c + 8)]);
            *reinterpret_cast<uint4*>(&outg[(size_t)(m0 + row) * H_DIM + c]) = w0;
            *reinterpret_cast<uint4*>(&outg[(size_t)(m0 + row) * H_DIM + c + 8]) = w1;
        }

        #pragma unroll
        for (int oc = 0; oc < 4; ++oc) {
            const float bb = bv[oc * 16 + l15];
            const int h = oc * 16 + l15;
            uint2 pw;
            pw.x = cvtpk(acc[2][oc][0] + bb, acc[2][oc][1] + bb);
            pw.y = cvtpk(acc[2][oc][2] + bb, acc[2][oc][3] + bb);
            *reinterpret_cast<uint2*>(&stage[h * 16 + lg * 4]) = pw;
        }
        const int h = lane;
        uint4 v0 = *reinterpret_cast<const uint4*>(&stage[h * 16]);
        uint4 v1 = *reinterpret_cast<const uint4*>(&stage[h * 16 + 8]);
        unsigned short* vrow = &vtb[((size_t)batch * H_DIM + h) * T_CTX + t0];
        *reinterpret_cast<uint4*>(&vrow[0]) = v0;
        *reinterpret_cast<uint4*>(&vrow[8]) = v1;
    }
}

// ---------------------------------------------------------------------------
// Repack k (row-major) and vt ([b][h][t]) into MFMA-FRAGMENT-MAJOR buffers:
// each fragment = contiguous 1KB wave-stream for attn's TA-coalesced loads.
//   kfb[((b*64+tt)*8 + hs*4+ct)*512 + lane*8+i] = K[tt*64+ct*16+(lane&15)]
//                                                  [hs*32+(lane>>4)*8+i]
//   vfb[((b*64+tt)*8 + oc*2+ks)*512 + lane*8+i] = V^T[oc*16+(lane&15)]
//                                                  [ks*32+(lane>>4)*8+i]
// Block = one 64-row tile: stage both tiles swizzled (coalesced), then each
// of the 8 waves emits one K fragment + one V fragment.
// ---------------------------------------------------------------------------
__global__ __launch_bounds__(512)
void repack_kv(const unsigned short* __restrict__ kb,
               const unsigned short* __restrict__ vtb,
               unsigned short* __restrict__ kfb,
               unsigned short* __restrict__ vfb)
{
    const int b  = blockIdx.x >> 6;
    const int tt = blockIdx.x & 63;
    const int tid = threadIdx.x;
    const int lane = tid & 63, wv = tid >> 6;
    const int l15 = lane & 15, lg = lane >> 4;
    const int kof = lg * 8;

    __shared__ unsigned short Ks[64 * 64];   // [t_local][h] swizzled
    __shared__ unsigned short Vt[64 * 64];   // [h][t_local] swizzled

    {
        const int row = tid >> 3;            // 0..63
        const int c8  = (tid & 7) * 8;       // 0..56
        uint4 kw = *reinterpret_cast<const uint4*>(
            &kb[((size_t)b * T_CTX + tt * 64 + row) * H_DIM + c8]);
        *reinterpret_cast<uint4*>(&Ks[swz(row, c8)]) = kw;
        uint4 vw = *reinterpret_cast<const uint4*>(
            &vtb[((size_t)b * H_DIM + row) * T_CTX + tt * 64 + c8]);
        *reinterpret_cast<uint4*>(&Vt[swz(row, c8)]) = vw;
    }
    __syncthreads();

    {
        const int g = wv;                    // 0..7
        const int hs = g >> 2, ct = g & 3;   // K: g = hs*4 + ct
        uint4 kw = *reinterpret_cast<const uint4*>(
            &Ks[swz(ct * 16 + l15, hs * 32 + kof)]);
        *reinterpret_cast<uint4*>(
            &kfb[(((size_t)b * 64 + tt) * 8 + g) * 512 + lane * 8]) = kw;
        const int oc = g >> 1, ks = g & 1;   // V: g = oc*2 + ks
        uint4 vw = *reinterpret_cast<const uint4*>(
            &Vt[swz(oc * 16 + l15, ks * 32 + kof)]);
        *reinterpret_cast<uint4*>(
            &vfb[(((size_t)b * 64 + tt) * 8 + g) * 512 + lane * 8]) = vw;
    }
}

// ---------------------------------------------------------------------------
// Causal flash attention — EXACT r14 version (passing, ~12us).
// Complementary-pair schedule, fragment-major K/V (1KB wave-streams).
// ---------------------------------------------------------------------------
__global__ __launch_bounds__(512)
void attn_kernel(const unsigned short* __restrict__ qg,
                 const unsigned short* __restrict__ kfb,
                 const unsigned short* __restrict__ vfb,
                 float* __restrict__ outp)
{
    const int tid  = threadIdx.x;
    const int lane = tid & 63, wv = tid >> 6;   // wv 0..7
    const int l15 = lane & 15, lg = lane >> 4;
    const int kof = lg * 8;

    __shared__ float smem[8448];                // Pt (32KB) ∪ merge (33KB)
    unsigned short* Pt = (unsigned short*)smem;
    const int pbase = wv * 2048;                // per-wave [32][64] bf16

    #pragma unroll 1
    for (int half = 0; half < 2; ++half) {
        const int r     = half ? (511 - (int)blockIdx.x) : (int)blockIdx.x;
        const int st    = 127 - (r >> 2);
        const int batch = r & 3;
        const int q0    = st * 32;
        const int nkv   = st / 2 + 1;           // 64-wide kv tiles
        const size_t rbase = (size_t)batch * T_CTX;
        const size_t fbase = (size_t)(batch * 64) * 8 * 512 + (size_t)lane * 8;

        __syncthreads();   // previous unit's merge reads done before Pt reuse

        short8_t qlo[2], qhi[2];
        #pragma unroll
        for (int hs = 0; hs < 2; ++hs) {
            qlo[hs] = *reinterpret_cast<const short8_t*>(
                &qg[(rbase + q0 + l15) * H_DIM + hs * 32 + kof]);
            qhi[hs] = *reinterpret_cast<const short8_t*>(
                &qg[(rbase + q0 + 16 + l15) * H_DIM + hs * 32 + kof]);
        }

        f32x4 olo[4] = {}, ohi[4] = {};
        float mlo = -1e30f, mhi = -1e30f, llo = 0.f, lhi = 0.f;

        // 1-deep K prefetch: kfC holds tile t's K fragments (contiguous loads)
        short8_t kfC[8];
        if (wv < nkv) {
            const unsigned short* kp = kfb + fbase + (size_t)wv * 8 * 512;
            #pragma unroll
            for (int i = 0; i < 8; ++i)
                kfC[i] = *reinterpret_cast<const short8_t*>(kp + i * 512);
        }

        for (int t = wv; t < nkv; t += 8) {
            const int k0 = t * 64;

            // V fragments issued EARLY (consumed after softmax)
            const unsigned short* vp = vfb + fbase + (size_t)t * 8 * 512;
            short8_t vf[8];
            #pragma unroll
            for (int g = 0; g < 8; ++g)
                vf[g] = *reinterpret_cast<const short8_t*>(vp + g * 512);

            // next tile's K issued EARLY (consumed next iteration)
            short8_t kfN[8];
            const bool havN = (t + 8 < nkv);
            if (havN) {
                const unsigned short* kp = kfb + fbase + (size_t)(t + 8) * 8 * 512;
                #pragma unroll
                for (int i = 0; i < 8; ++i)
                    kfN[i] = *reinterpret_cast<const short8_t*>(kp + i * 512);
            }

            f32x4 slo[4] = {}, shi[4] = {};
            #pragma unroll
            for (int hs = 0; hs < 2; ++hs)
                #pragma unroll
                for (int ct = 0; ct < 4; ++ct) {
                    slo[ct] = __builtin_amdgcn_mfma_f32_16x16x32_bf16(
                        kfC[hs * 4 + ct], qlo[hs], slo[ct], 0, 0, 0);
                    shi[ct] = __builtin_amdgcn_mfma_f32_16x16x32_bf16(
                        kfC[hs * 4 + ct], qhi[hs], shi[ct], 0, 0, 0);
                }

            if (t == nkv - 1) {   // only the strip's last tile crosses the diagonal
                #pragma unroll
                for (int ct = 0; ct < 4; ++ct)
                    #pragma unroll
                    for (int rr = 0; rr < 4; ++rr) {
                        const int kv = k0 + ct * 16 + lg * 4 + rr;
                        if (kv > q0 + l15)      slo[ct][rr] = -1e30f;
                        if (kv > q0 + 16 + l15) shi[ct][rr] = -1e30f;
                    }
            }

            float mxlo, mxhi;
            {
                float a = fmaxf(fmaxf(slo[0][0], slo[0][1]), fmaxf(slo[0][2], slo[0][3]));
                float b = fmaxf(fmaxf(slo[1][0], slo[1][1]), fmaxf(slo[1][2], slo[1][3]));
                float c = fmaxf(fmaxf(slo[2][0], slo[2][1]), fmaxf(slo[2][2], slo[2][3]));
                float d = fmaxf(fmaxf(slo[3][0], slo[3][1]), fmaxf(slo[3][2], slo[3][3]));
                mxlo = fmaxf(fmaxf(a, b), fmaxf(c, d));
                a = fmaxf(fmaxf(shi[0][0], shi[0][1]), fmaxf(shi[0][2], shi[0][3]));
                b = fmaxf(fmaxf(shi[1][0], shi[1][1]), fmaxf(shi[1][2], shi[1][3]));
                c = fmaxf(fmaxf(shi[2][0], shi[2][1]), fmaxf(shi[2][2], shi[2][3]));
                d = fmaxf(fmaxf(shi[3][0], shi[3][1]), fmaxf(shi[3][2], shi[3][3]));
                mxhi = fmaxf(fmaxf(a, b), fmaxf(c, d));
            }
            mxlo = fmaxf(mxlo, __shfl_xor(mxlo, 16));
            mxlo = fmaxf(mxlo, __shfl_xor(mxlo, 32));
            mxhi = fmaxf(mxhi, __shfl_xor(mxhi, 16));
            mxhi = fmaxf(mxhi, __shfl_xor(mxhi, 32));

            if (!__all((mxlo <= mlo + DEFER_THR) && (mxhi <= mhi + DEFER_THR))) {
                const float nmlo = fmaxf(mlo, mxlo), nmhi = fmaxf(mhi, mxhi);
                const float cflo = fexp2(mlo - nmlo), cfhi = fexp2(mhi - nmhi);
                llo *= cflo; lhi *= cfhi;
                mlo = nmlo; mhi = nmhi;
                #pragma unroll
                for (int rr = 0; rr < 4; ++rr) {
                    const float cl = __shfl(cflo, lg * 4 + rr);
                    const float ch = __shfl(cfhi, lg * 4 + rr);
                    #pragma unroll
                    for (int oc = 0; oc < 4; ++oc) { olo[oc][rr] *= cl; ohi[oc][rr] *= ch; }
                }
            }

            float rllo = 0.f, rlhi = 0.f;
            #pragma unroll
            for (int ct = 0; ct < 4; ++ct) {
                const float p0 = fexp2(slo[ct][0] - mlo), p1 = fexp2(slo[ct][1] - mlo);
                const float p2 = fexp2(slo[ct][2] - mlo), p3 = fexp2(slo[ct][3] - mlo);
                rllo += (p0 + p1) + (p2 + p3);
                uint2 pw; pw.x = cvtpk(p0, p1); pw.y = cvtpk(p2, p3);
                *reinterpret_cast<uint2*>(&Pt[pbase + swz(l15, ct * 16 + lg * 4)]) = pw;
                const float h0 = fexp2(shi[ct][0] - mhi), h1 = fexp2(shi[ct][1] - mhi);
                const float h2 = fexp2(shi[ct][2] - mhi), h3 = fexp2(shi[ct][3] - mhi);
                rlhi += (h0 + h1) + (h2 + h3);
                uint2 ph; ph.x = cvtpk(h0, h1); ph.y = cvtpk(h2, h3);
                *reinterpret_cast<uint2*>(&Pt[pbase + swz(16 + l15, ct * 16 + lg * 4)]) = ph;
            }
            rllo += __shfl_xor(rllo, 16); rllo += __shfl_xor(rllo, 32);
            rlhi += __shfl_xor(rlhi, 16); rlhi += __shfl_xor(rlhi, 32);
            llo += rllo; lhi += rlhi;

            #pragma unroll
            for (int ks = 0; ks < 2; ++ks) {
                const short8_t palo = *reinterpret_cast<const short8_t*>(
                    &Pt[pbase + swz(l15, ks * 32 + kof)]);
                const short8_t pahi = *reinterpret_cast<const short8_t*>(
                    &Pt[pbase + swz(16 + l15, ks * 32 + kof)]);
                #pragma unroll
                for (int oc = 0; oc < 4; ++oc) {
                    olo[oc] = __builtin_amdgcn_mfma_f32_16x16x32_bf16(
                        palo, vf[oc * 2 + ks], olo[oc], 0, 0, 0);
                    ohi[oc] = __builtin_amdgcn_mfma_f32_16x16x32_bf16(
                        pahi, vf[oc * 2 + ks], ohi[oc], 0, 0, 0);
                }
            }

            if (havN) {
                #pragma unroll
                for (int i = 0; i < 8; ++i) kfC[i] = kfN[i];
            }
        }

        // ---- two-phase merge + DIRECT output: ph 0 = lo rows, 1 = hi rows ----
        #pragma unroll 1
        for (int ph = 0; ph < 2; ++ph) {
            __syncthreads();
            #pragma unroll
            for (int oc = 0; oc < 4; ++oc)
                #pragma unroll
                for (int rr = 0; rr < 4; ++rr)
                    smem[wv * 1024 + (lg * 4 + rr) * 64 + oc * 16 + l15] =
                        ph ? ohi[oc][rr] : olo[oc][rr];
            if (lg == 0) {
                smem[8192 + wv * 16 + l15] = ph ? mhi : mlo;
                smem[8320 + wv * 16 + l15] = ph ? lhi : llo;
            }
            __syncthreads();
            const int row = tid >> 5;          // 0..15
            const int c2  = (tid & 31) * 2;
            float M = -1e30f;
            #pragma unroll
            for (int w = 0; w < 8; ++w) M = fmaxf(M, smem[8192 + w * 16 + row]);
            float L = 0.f, a0 = 0.f, a1 = 0.f;
            #pragma unroll
            for (int w = 0; w < 8; ++w) {
                const float e = fexp2(smem[8192 + w * 16 + row] - M);
                L += e * smem[8320 + w * 16 + row];
                a0 += e * smem[w * 1024 + row * 64 + c2];
                a1 += e * smem[w * 1024 + row * 64 + c2 + 1];
            }
            const float inv = 1.0f / L;
            float2 rr2; rr2.x = a0 * inv; rr2.y = a1 * inv;
            *reinterpret_cast<float2*>(
                &outp[(rbase + q0 + ph * 16 + row) * H_DIM + c2]) = rr2;
        }
    }
}

extern "C" void kernel_launch(void* const* d_in, const int* in_sizes, int n_in,
                              void* d_out, int out_size, void* d_ws, size_t ws_size,
                              hipStream_t stream) {
    const float* x  = (const float*)d_in[0];
    const float* Wq = (const float*)d_in[1];
    const float* bq = (const float*)d_in[2];
    const float* Wk = (const float*)d_in[3];
    const float* bk = (const float*)d_in[4];
    const float* Wv = (const float*)d_in[5];
    const float* bv = (const float*)d_in[6];
    float* out = (float*)d_out;

    // ws (ushort): wt | qb | kb | vtb | kfb | vfb  (~10.9 MB)
    unsigned short* wt  = (unsigned short*)d_ws;
    unsigned short* qb  = wt  + 3 * H_DIM * E_DIM;
    unsigned short* kb  = qb  + (size_t)M_ROWS * H_DIM;
    unsigned short* vtb = kb  + (size_t)M_ROWS * H_DIM;
    unsigned short* kfb = vtb + (size_t)B_SZ * H_DIM * T_CTX;
    unsigned short* vfb = kfb + (size_t)M_ROWS * H_DIM;

    prep_weights<<<dim3(E_DIM / 64, 3), 256, 0, stream>>>(Wq, Wk, Wv, wt);
    proj_kernel<<<dim3(M_ROWS / 64), 512, 0, stream>>>(x, wt, bq, bk, bv, qb, kb, vtb);
    repack_kv<<<dim3(B_SZ * 64), 512, 0, stream>>>(kb, vtb, kfb, vfb);
    attn_kernel<<<dim3(256), 512, 0, stream>>>(qb, kfb, vfb, out);
}

// Round 16
// 55.317 us; speedup vs baseline: 1.9688x; 1.0167x over previous
//
#include <hip/hip_runtime.h>

typedef __attribute__((ext_vector_type(8))) short short8_t;
typedef __attribute__((ext_vector_type(4))) float f32x4;

namespace {
constexpr int T_CTX  = 4096;
constexpr int E_DIM  = 1024;
constexpr int H_DIM  = 64;
constexpr int B_SZ   = 4;
constexpr int M_ROWS = B_SZ * T_CTX; // 16384
// 1/sqrt(H) * log2(e): S lands in log2 domain -> softmax via exp2
constexpr float SCALE_Q = 0.125f * 1.4426950408889634f;
constexpr float DEFER_THR = 8.0f;    // log2 units; P bounded by 2^8
}

__device__ __forceinline__ unsigned short f2bf(float f) {
    unsigned u = __builtin_bit_cast(unsigned, f);
    u += 0x7fffu + ((u >> 16) & 1u);          // RNE
    return (unsigned short)(u >> 16);
}
__device__ __forceinline__ unsigned pack2(unsigned short lo, unsigned short hi) {
    return (unsigned)lo | ((unsigned)hi << 16);
}
__device__ __forceinline__ unsigned cvtpk(float lo, float hi) {
    unsigned r;
    asm("v_cvt_pk_bf16_f32 %0, %1, %2" : "=v"(r) : "v"(lo), "v"(hi));
    return r;
}
__device__ __forceinline__ float fexp2(float x) {   // guaranteed v_exp_f32
    float r;
    asm("v_exp_f32 %0, %1" : "=v"(r) : "v"(x));
    return r;
}
// swizzled ushort index into a row-major [rows][64] bf16 LDS tile
__device__ __forceinline__ int swz(int row, int col) {
    return row * 64 + (col ^ ((row & 7) << 3));
}

// ---------------------------------------------------------------------------
// Weight prep: W[1024][64] fp32 -> FRAGMENT-MAJOR bf16 layout (1KB streams).
// ---------------------------------------------------------------------------
__global__ __launch_bounds__(256)
void prep_weights(const float* __restrict__ Wq, const float* __restrict__ Wk,
                  const float* __restrict__ Wv, unsigned short* __restrict__ wt)
{
    const int mat = blockIdx.y;
    const int kc  = blockIdx.x;
    const float* W = (mat == 0) ? Wq : (mat == 1) ? Wk : Wv;
    __shared__ float Ls[64][65];   // Ls[n][k_local]
    const int tid = threadIdx.x;
    const int kb = kc * 64;
    #pragma unroll
    for (int j = 0; j < 4; ++j) {
        int p = j * 256 + tid;
        int kr = p >> 4, c4 = (p & 15) * 4;
        float4 w4 = *reinterpret_cast<const float4*>(&W[(size_t)(kb + kr) * H_DIM + c4]);
        Ls[c4 + 0][kr] = w4.x; Ls[c4 + 1][kr] = w4.y;
        Ls[c4 + 2][kr] = w4.z; Ls[c4 + 3][kr] = w4.w;
    }
    __syncthreads();
    #pragma unroll
    for (int j = 0; j < 2; ++j) {
        int p = j * 256 + tid;       // 0..511
        int f  = p >> 6;             // 0..7 = oc*2 + hs
        int ln = p & 63;
        int n   = (f >> 1) * 16 + (ln & 15);
        int kb8 = (f & 1) * 32 + (ln >> 4) * 8;
        uint4 w;
        w.x = pack2(f2bf(Ls[n][kb8 + 0]), f2bf(Ls[n][kb8 + 1]));
        w.y = pack2(f2bf(Ls[n][kb8 + 2]), f2bf(Ls[n][kb8 + 3]));
        w.z = pack2(f2bf(Ls[n][kb8 + 4]), f2bf(Ls[n][kb8 + 5]));
        w.w = pack2(f2bf(Ls[n][kb8 + 6]), f2bf(Ls[n][kb8 + 7]));
        size_t off = ((size_t)(kc * 24 + mat * 8 + f) * 64 + ln) * 8;
        *reinterpret_cast<uint4*>(&wt[off]) = w;
    }
}

// ---------------------------------------------------------------------------
// Fused QKV projection — r13 structure (known-fast codegen). ONLY change:
// the k output is stored as MFMA FRAGMENTS (kfb) instead of row-major.
// Same one-pass 50KB merge, same Stg staging, same store count — only the
// k-block's Stg read/store addressing differs (r14 lesson: Vst + two-pass
// merge flipped the allocator to VGPR=64; those stay OUT of proj).
// Emits: q row-major (pre-scaled), kfb fragment-major, v transposed vt[b][h][t].
// ---------------------------------------------------------------------------
__global__ __launch_bounds__(512, 1)
void proj_kernel(const float* __restrict__ x, const unsigned short* __restrict__ wt,
                 const float* __restrict__ bq, const float* __restrict__ bk,
                 const float* __restrict__ bv,
                 unsigned short* __restrict__ qb, unsigned short* __restrict__ kfb,
                 unsigned short* __restrict__ vtb)
{
    const int tid = threadIdx.x;
    const int lane = tid & 63, wv = tid >> 6;   // wv 0..7
    const int l15 = lane & 15, lg = lane >> 4;
    const int kof = lg * 8;

    const int rg = wv & 3;                      // row-group (= ct quarter)
    const int kh = wv >> 2;                     // k-half
    const int m0    = blockIdx.x * 64 + rg * 16;
    const int batch = m0 >> 12;
    const int t0    = m0 & (T_CTX - 1);
    const int tt    = blockIdx.x & 63;          // 64-row tile index in batch
    const int kbeg  = kh * 512;

    f32x4 acc[3][4] = {};
    const float* xrow = &x[(size_t)(m0 + l15) * E_DIM + kof];
    const unsigned short* wlane = wt + (size_t)lane * 8;   // lane-folded

    float4 xa0 = *reinterpret_cast<const float4*>(xrow + kbeg);
    float4 xb0 = *reinterpret_cast<const float4*>(xrow + kbeg + 4);
    float4 xa1 = *reinterpret_cast<const float4*>(xrow + kbeg + 32);
    float4 xb1 = *reinterpret_cast<const float4*>(xrow + kbeg + 36);

    for (int k0 = kbeg; k0 < kbeg + 512; k0 += 32) {
        const int kn = (k0 + 64 < kbeg + 512) ? k0 + 64 : kbeg;
        float4 na = *reinterpret_cast<const float4*>(xrow + kn);
        float4 nb = *reinterpret_cast<const float4*>(xrow + kn + 4);

        const int fb = (k0 >> 6) * 24 + ((k0 >> 5) & 1);
        short8_t bf[12];
        #pragma unroll
        for (int mat = 0; mat < 3; ++mat)
            #pragma unroll
            for (int oc = 0; oc < 4; ++oc)
                bf[mat * 4 + oc] = *reinterpret_cast<const short8_t*>(
                    wlane + (size_t)(fb + mat * 8 + oc * 2) * 512);

        uint4 au;
        au.x = cvtpk(xa0.x, xa0.y); au.y = cvtpk(xa0.z, xa0.w);
        au.z = cvtpk(xb0.x, xb0.y); au.w = cvtpk(xb0.z, xb0.w);
        const short8_t a = __builtin_bit_cast(short8_t, au);

        #pragma unroll
        for (int mat = 0; mat < 3; ++mat)
            #pragma unroll
            for (int oc = 0; oc < 4; ++oc)
                acc[mat][oc] = __builtin_amdgcn_mfma_f32_16x16x32_bf16(
                    a, bf[mat * 4 + oc], acc[mat][oc], 0, 0, 0);

        xa0 = xa1; xb0 = xb1; xa1 = na; xb1 = nb;
    }

    __shared__ float Ms[4][64][49];              // 50 KB fp32 merge (one pass)
    __shared__ unsigned short Stg[4][1024];      // 8 KB bf16 staging (NO alias)
    if (kh == 1) {
        #pragma unroll
        for (int mat = 0; mat < 3; ++mat)
            #pragma unroll
            for (int oc = 0; oc < 4; ++oc)
                #pragma unroll
                for (int r = 0; r < 4; ++r)
                    Ms[rg][lane][(mat * 4 + oc) * 4 + r] = acc[mat][oc][r];
    }
    __syncthreads();
    if (kh == 0) {
        #pragma unroll
        for (int mat = 0; mat < 3; ++mat)
            #pragma unroll
            for (int oc = 0; oc < 4; ++oc)
                #pragma unroll
                for (int r = 0; r < 4; ++r)
                    acc[mat][oc][r] += Ms[rg][lane][(mat * 4 + oc) * 4 + r];

        unsigned short* stage = &Stg[rg][0];

        // ---- q: stage swizzled -> coalesced row-major write ----
        #pragma unroll
        for (int oc = 0; oc < 4; ++oc) {
            const float bb = bq[oc * 16 + l15];
            #pragma unroll
            for (int r = 0; r < 4; ++r)
                stage[swz(lg * 4 + r, oc * 16 + l15)] =
                    f2bf((acc[0][oc][r] + bb) * SCALE_Q);
        }
        {
            const int row = lane >> 2, c = (lane & 3) * 16;
            uint4 w0 = *reinterpret_cast<const uint4*>(&stage[swz(row, c)]);
            uint4 w1 = *reinterpret_cast<const uint4*>(&stage[swz(row, c + 8)]);
            *reinterpret_cast<uint4*>(&qb[(size_t)(m0 + row) * H_DIM + c]) = w0;
            *reinterpret_cast<uint4*>(&qb[(size_t)(m0 + row) * H_DIM + c + 8]) = w1;
        }

        // ---- k: stage swizzled -> 2 FRAGMENT stores (this rg == ct) ----
        #pragma unroll
        for (int oc = 0; oc < 4; ++oc) {
            const float bb = bk[oc * 16 + l15];
            #pragma unroll
            for (int r = 0; r < 4; ++r)
                stage[swz(lg * 4 + r, oc * 16 + l15)] =
                    f2bf(acc[1][oc][r] + bb);
        }
        #pragma unroll
        for (int hs = 0; hs < 2; ++hs) {
            uint4 w = *reinterpret_cast<const uint4*>(&stage[swz(l15, hs * 32 + kof)]);
            *reinterpret_cast<uint4*>(
                &kfb[(((size_t)batch * 64 + tt) * 8 + hs * 4 + rg) * 512 + lane * 8]) = w;
        }

        // ---- v: transposed rows vt[b][h][t] (r13 pattern) ----
        #pragma unroll
        for (int oc = 0; oc < 4; ++oc) {
            const float bb = bv[oc * 16 + l15];
            const int h = oc * 16 + l15;
            uint2 pw;
            pw.x = cvtpk(acc[2][oc][0] + bb, acc[2][oc][1] + bb);
            pw.y = cvtpk(acc[2][oc][2] + bb, acc[2][oc][3] + bb);
            *reinterpret_cast<uint2*>(&stage[h * 16 + lg * 4]) = pw;
        }
        const int h = lane;
        uint4 v0 = *reinterpret_cast<const uint4*>(&stage[h * 16]);
        uint4 v1 = *reinterpret_cast<const uint4*>(&stage[h * 16 + 8]);
        unsigned short* vrow = &vtb[((size_t)batch * H_DIM + h) * T_CTX + t0];
        *reinterpret_cast<uint4*>(&vrow[0]) = v0;
        *reinterpret_cast<uint4*>(&vrow[8]) = v1;
    }
}

// ---------------------------------------------------------------------------
// Repack V only: vt[b][h][t] -> fragment-major vfb (1KB wave-streams).
//   vfb[((b*64+tt)*8 + oc*2+ks)*512 + lane*8+i] = V^T[oc*16+(lane&15)]
//                                                  [ks*32+(lane>>4)*8+i]
// Block = one 64-col tile: stage swizzled (coalesced 16B reads along t),
// then each of the 8 waves emits one fragment.
// ---------------------------------------------------------------------------
__global__ __launch_bounds__(512)
void repack_v(const unsigned short* __restrict__ vtb,
              unsigned short* __restrict__ vfb)
{
    const int b  = blockIdx.x >> 6;
    const int tt = blockIdx.x & 63;
    const int tid = threadIdx.x;
    const int lane = tid & 63, wv = tid >> 6;
    const int l15 = lane & 15, lg = lane >> 4;
    const int kof = lg * 8;

    __shared__ unsigned short Vt[64 * 64];   // [h][t_local] swizzled

    {
        const int row = tid >> 3;            // h = 0..63
        const int c8  = (tid & 7) * 8;       // t_local
        uint4 vw = *reinterpret_cast<const uint4*>(
            &vtb[((size_t)b * H_DIM + row) * T_CTX + tt * 64 + c8]);
        *reinterpret_cast<uint4*>(&Vt[swz(row, c8)]) = vw;
    }
    __syncthreads();

    {
        const int g = wv;                    // 0..7 = oc*2 + ks
        const int oc = g >> 1, ks = g & 1;
        uint4 vw = *reinterpret_cast<const uint4*>(
            &Vt[swz(oc * 16 + l15, ks * 32 + kof)]);
        *reinterpret_cast<uint4*>(
            &vfb[(((size_t)b * 64 + tt) * 8 + g) * 512 + lane * 8]) = vw;
    }
}

// ---------------------------------------------------------------------------
// Causal flash attention — EXACT r14 version (passing, ~11us).
// Complementary-pair schedule, fragment-major K/V (1KB wave-streams).
// ---------------------------------------------------------------------------
__global__ __launch_bounds__(512)
void attn_kernel(const unsigned short* __restrict__ qg,
                 const unsigned short* __restrict__ kfb,
                 const unsigned short* __restrict__ vfb,
                 float* __restrict__ outp)
{
    const int tid  = threadIdx.x;
    const int lane = tid & 63, wv = tid >> 6;   // wv 0..7
    const int l15 = lane & 15, lg = lane >> 4;
    const int kof = lg * 8;

    __shared__ float smem[8448];                // Pt (32KB) ∪ merge (33KB)
    unsigned short* Pt = (unsigned short*)smem;
    const int pbase = wv * 2048;                // per-wave [32][64] bf16

    #pragma unroll 1
    for (int half = 0; half < 2; ++half) {
        const int r     = half ? (511 - (int)blockIdx.x) : (int)blockIdx.x;
        const int st    = 127 - (r >> 2);
        const int batch = r & 3;
        const int q0    = st * 32;
        const int nkv   = st / 2 + 1;           // 64-wide kv tiles
        const size_t rbase = (size_t)batch * T_CTX;
        const size_t fbase = (size_t)(batch * 64) * 8 * 512 + (size_t)lane * 8;

        __syncthreads();   // previous unit's merge reads done before Pt reuse

        short8_t qlo[2], qhi[2];
        #pragma unroll
        for (int hs = 0; hs < 2; ++hs) {
            qlo[hs] = *reinterpret_cast<const short8_t*>(
                &qg[(rbase + q0 + l15) * H_DIM + hs * 32 + kof]);
            qhi[hs] = *reinterpret_cast<const short8_t*>(
                &qg[(rbase + q0 + 16 + l15) * H_DIM + hs * 32 + kof]);
        }

        f32x4 olo[4] = {}, ohi[4] = {};
        float mlo = -1e30f, mhi = -1e30f, llo = 0.f, lhi = 0.f;

        // 1-deep K prefetch: kfC holds tile t's K fragments (contiguous loads)
        short8_t kfC[8];
        if (wv < nkv) {
            const unsigned short* kp = kfb + fbase + (size_t)wv * 8 * 512;
            #pragma unroll
            for (int i = 0; i < 8; ++i)
                kfC[i] = *reinterpret_cast<const short8_t*>(kp + i * 512);
        }

        for (int t = wv; t < nkv; t += 8) {
            const int k0 = t * 64;

            // V fragments issued EARLY (consumed after softmax)
            const unsigned short* vp = vfb + fbase + (size_t)t * 8 * 512;
            short8_t vf[8];
            #pragma unroll
            for (int g = 0; g < 8; ++g)
                vf[g] = *reinterpret_cast<const short8_t*>(vp + g * 512);

            // next tile's K issued EARLY (consumed next iteration)
            short8_t kfN[8];
            const bool havN = (t + 8 < nkv);
            if (havN) {
                const unsigned short* kp = kfb + fbase + (size_t)(t + 8) * 8 * 512;
                #pragma unroll
                for (int i = 0; i < 8; ++i)
                    kfN[i] = *reinterpret_cast<const short8_t*>(kp + i * 512);
            }

            f32x4 slo[4] = {}, shi[4] = {};
            #pragma unroll
            for (int hs = 0; hs < 2; ++hs)
                #pragma unroll
                for (int ct = 0; ct < 4; ++ct) {
                    slo[ct] = __builtin_amdgcn_mfma_f32_16x16x32_bf16(
                        kfC[hs * 4 + ct], qlo[hs], slo[ct], 0, 0, 0);
                    shi[ct] = __builtin_amdgcn_mfma_f32_16x16x32_bf16(
                        kfC[hs * 4 + ct], qhi[hs], shi[ct], 0, 0, 0);
                }

            if (t == nkv - 1) {   // only the strip's last tile crosses the diagonal
                #pragma unroll
                for (int ct = 0; ct < 4; ++ct)
                    #pragma unroll
                    for (int rr = 0; rr < 4; ++rr) {
                        const int kv = k0 + ct * 16 + lg * 4 + rr;
                        if (kv > q0 + l15)      slo[ct][rr] = -1e30f;
                        if (kv > q0 + 16 + l15) shi[ct][rr] = -1e30f;
                    }
            }

            float mxlo, mxhi;
            {
                float a = fmaxf(fmaxf(slo[0][0], slo[0][1]), fmaxf(slo[0][2], slo[0][3]));
                float b = fmaxf(fmaxf(slo[1][0], slo[1][1]), fmaxf(slo[1][2], slo[1][3]));
                float c = fmaxf(fmaxf(slo[2][0], slo[2][1]), fmaxf(slo[2][2], slo[2][3]));
                float d = fmaxf(fmaxf(slo[3][0], slo[3][1]), fmaxf(slo[3][2], slo[3][3]));
                mxlo = fmaxf(fmaxf(a, b), fmaxf(c, d));
                a = fmaxf(fmaxf(shi[0][0], shi[0][1]), fmaxf(shi[0][2], shi[0][3]));
                b = fmaxf(fmaxf(shi[1][0], shi[1][1]), fmaxf(shi[1][2], shi[1][3]));
                c = fmaxf(fmaxf(shi[2][0], shi[2][1]), fmaxf(shi[2][2], shi[2][3]));
                d = fmaxf(fmaxf(shi[3][0], shi[3][1]), fmaxf(shi[3][2], shi[3][3]));
                mxhi = fmaxf(fmaxf(a, b), fmaxf(c, d));
            }
            mxlo = fmaxf(mxlo, __shfl_xor(mxlo, 16));
            mxlo = fmaxf(mxlo, __shfl_xor(mxlo, 32));
            mxhi = fmaxf(mxhi, __shfl_xor(mxhi, 16));
            mxhi = fmaxf(mxhi, __shfl_xor(mxhi, 32));

            if (!__all((mxlo <= mlo + DEFER_THR) && (mxhi <= mhi + DEFER_THR))) {
                const float nmlo = fmaxf(mlo, mxlo), nmhi = fmaxf(mhi, mxhi);
                const float cflo = fexp2(mlo - nmlo), cfhi = fexp2(mhi - nmhi);
                llo *= cflo; lhi *= cfhi;
                mlo = nmlo; mhi = nmhi;
                #pragma unroll
                for (int rr = 0; rr < 4; ++rr) {
                    const float cl = __shfl(cflo, lg * 4 + rr);
                    const float ch = __shfl(cfhi, lg * 4 + rr);
                    #pragma unroll
                    for (int oc = 0; oc < 4; ++oc) { olo[oc][rr] *= cl; ohi[oc][rr] *= ch; }
                }
            }

            float rllo = 0.f, rlhi = 0.f;
            #pragma unroll
            for (int ct = 0; ct < 4; ++ct) {
                const float p0 = fexp2(slo[ct][0] - mlo), p1 = fexp2(slo[ct][1] - mlo);
                const float p2 = fexp2(slo[ct][2] - mlo), p3 = fexp2(slo[ct][3] - mlo);
                rllo += (p0 + p1) + (p2 + p3);
                uint2 pw; pw.x = cvtpk(p0, p1); pw.y = cvtpk(p2, p3);
                *reinterpret_cast<uint2*>(&Pt[pbase + swz(l15, ct * 16 + lg * 4)]) = pw;
                const float h0 = fexp2(shi[ct][0] - mhi), h1 = fexp2(shi[ct][1] - mhi);
                const float h2 = fexp2(shi[ct][2] - mhi), h3 = fexp2(shi[ct][3] - mhi);
                rlhi += (h0 + h1) + (h2 + h3);
                uint2 ph; ph.x = cvtpk(h0, h1); ph.y = cvtpk(h2, h3);
                *reinterpret_cast<uint2*>(&Pt[pbase + swz(16 + l15, ct * 16 + lg * 4)]) = ph;
            }
            rllo += __shfl_xor(rllo, 16); rllo += __shfl_xor(rllo, 32);
            rlhi += __shfl_xor(rlhi, 16); rlhi += __shfl_xor(rlhi, 32);
            llo += rllo; lhi += rlhi;

            #pragma unroll
            for (int ks = 0; ks < 2; ++ks) {
                const short8_t palo = *reinterpret_cast<const short8_t*>(
                    &Pt[pbase + swz(l15, ks * 32 + kof)]);
                const short8_t pahi = *reinterpret_cast<const short8_t*>(
                    &Pt[pbase + swz(16 + l15, ks * 32 + kof)]);
                #pragma unroll
                for (int oc = 0; oc < 4; ++oc) {
                    olo[oc] = __builtin_amdgcn_mfma_f32_16x16x32_bf16(
                        palo, vf[oc * 2 + ks], olo[oc], 0, 0, 0);
                    ohi[oc] = __builtin_amdgcn_mfma_f32_16x16x32_bf16(
                        pahi, vf[oc * 2 + ks], ohi[oc], 0, 0, 0);
                }
            }

            if (havN) {
                #pragma unroll
                for (int i = 0; i < 8; ++i) kfC[i] = kfN[i];
            }
        }

        // ---- two-phase merge + DIRECT output: ph 0 = lo rows, 1 = hi rows ----
        #pragma unroll 1
        for (int ph = 0; ph < 2; ++ph) {
            __syncthreads();
            #pragma unroll
            for (int oc = 0; oc < 4; ++oc)
                #pragma unroll
                for (int rr = 0; rr < 4; ++rr)
                    smem[wv * 1024 + (lg * 4 + rr) * 64 + oc * 16 + l15] =
                        ph ? ohi[oc][rr] : olo[oc][rr];
            if (lg == 0) {
                smem[8192 + wv * 16 + l15] = ph ? mhi : mlo;
                smem[8320 + wv * 16 + l15] = ph ? lhi : llo;
            }
            __syncthreads();
            const int row = tid >> 5;          // 0..15
            const int c2  = (tid & 31) * 2;
            float M = -1e30f;
            #pragma unroll
            for (int w = 0; w < 8; ++w) M = fmaxf(M, smem[8192 + w * 16 + row]);
            float L = 0.f, a0 = 0.f, a1 = 0.f;
            #pragma unroll
            for (int w = 0; w < 8; ++w) {
                const float e = fexp2(smem[8192 + w * 16 + row] - M);
                L += e * smem[8320 + w * 16 + row];
                a0 += e * smem[w * 1024 + row * 64 + c2];
                a1 += e * smem[w * 1024 + row * 64 + c2 + 1];
            }
            const float inv = 1.0f / L;
            float2 rr2; rr2.x = a0 * inv; rr2.y = a1 * inv;
            *reinterpret_cast<float2*>(
                &outp[(rbase + q0 + ph * 16 + row) * H_DIM + c2]) = rr2;
        }
    }
}

extern "C" void kernel_launch(void* const* d_in, const int* in_sizes, int n_in,
                              void* d_out, int out_size, void* d_ws, size_t ws_size,
                              hipStream_t stream) {
    const float* x  = (const float*)d_in[0];
    const float* Wq = (const float*)d_in[1];
    const float* bq = (const float*)d_in[2];
    const float* Wk = (const float*)d_in[3];
    const float* bk = (const float*)d_in[4];
    const float* Wv = (const float*)d_in[5];
    const float* bv = (const float*)d_in[6];
    float* out = (float*)d_out;

    // ws (ushort): wt | qb | kfb | vtb | vfb  (~8.8 MB)
    unsigned short* wt  = (unsigned short*)d_ws;
    unsigned short* qb  = wt  + 3 * H_DIM * E_DIM;
    unsigned short* kfb = qb  + (size_t)M_ROWS * H_DIM;
    unsigned short* vtb = kfb + (size_t)M_ROWS * H_DIM;
    unsigned short* vfb = vtb + (size_t)B_SZ * H_DIM * T_CTX;

    prep_weights<<<dim3(E_DIM / 64, 3), 256, 0, stream>>>(Wq, Wk, Wv, wt);
    proj_kernel<<<dim3(M_ROWS / 64), 512, 0, stream>>>(x, wt, bq, bk, bv, qb, kfb, vtb);
    repack_v<<<dim3(B_SZ * 64), 512, 0, stream>>>(vtb, vfb);
    attn_kernel<<<dim3(256), 512, 0, stream>>>(qb, kfb, vfb, out);
}

// Round 18
// 55.264 us; speedup vs baseline: 1.9706x; 1.0009x over previous
//
#include <hip/hip_runtime.h>

typedef __attribute__((ext_vector_type(8))) short short8_t;
typedef __attribute__((ext_vector_type(4))) float f32x4;

namespace {
constexpr int T_CTX  = 4096;
constexpr int E_DIM  = 1024;
constexpr int H_DIM  = 64;
constexpr int B_SZ   = 4;
constexpr int M_ROWS = B_SZ * T_CTX; // 16384
// 1/sqrt(H) * log2(e): S lands in log2 domain -> softmax via exp2
constexpr float SCALE_Q = 0.125f * 1.4426950408889634f;
constexpr float DEFER_THR = 8.0f;    // log2 units; P bounded by 2^8
}

__device__ __forceinline__ unsigned short f2bf(float f) {
    unsigned u = __builtin_bit_cast(unsigned, f);
    u += 0x7fffu + ((u >> 16) & 1u);          // RNE
    return (unsigned short)(u >> 16);
}
__device__ __forceinline__ unsigned pack2(unsigned short lo, unsigned short hi) {
    return (unsigned)lo | ((unsigned)hi << 16);
}
__device__ __forceinline__ unsigned cvtpk(float lo, float hi) {
    unsigned r;
    asm("v_cvt_pk_bf16_f32 %0, %1, %2" : "=v"(r) : "v"(lo), "v"(hi));
    return r;
}
__device__ __forceinline__ float fexp2(float x) {   // guaranteed v_exp_f32
    float r;
    asm("v_exp_f32 %0, %1" : "=v"(r) : "v"(x));
    return r;
}
// swizzled ushort index into a row-major [rows][64] bf16 LDS tile
__device__ __forceinline__ int swz(int row, int col) {
    return row * 64 + (col ^ ((row & 7) << 3));
}

// ---------------------------------------------------------------------------
// Weight prep: W[1024][64] fp32 -> FRAGMENT-MAJOR bf16 layout (1KB streams).
// ---------------------------------------------------------------------------
__global__ __launch_bounds__(256)
void prep_weights(const float* __restrict__ Wq, const float* __restrict__ Wk,
                  const float* __restrict__ Wv, unsigned short* __restrict__ wt)
{
    const int mat = blockIdx.y;
    const int kc  = blockIdx.x;
    const float* W = (mat == 0) ? Wq : (mat == 1) ? Wk : Wv;
    __shared__ float Ls[64][65];   // Ls[n][k_local]
    const int tid = threadIdx.x;
    const int kb = kc * 64;
    #pragma unroll
    for (int j = 0; j < 4; ++j) {
        int p = j * 256 + tid;
        int kr = p >> 4, c4 = (p & 15) * 4;
        float4 w4 = *reinterpret_cast<const float4*>(&W[(size_t)(kb + kr) * H_DIM + c4]);
        Ls[c4 + 0][kr] = w4.x; Ls[c4 + 1][kr] = w4.y;
        Ls[c4 + 2][kr] = w4.z; Ls[c4 + 3][kr] = w4.w;
    }
    __syncthreads();
    #pragma unroll
    for (int j = 0; j < 2; ++j) {
        int p = j * 256 + tid;       // 0..511
        int f  = p >> 6;             // 0..7 = oc*2 + hs
        int ln = p & 63;
        int n   = (f >> 1) * 16 + (ln & 15);
        int kb8 = (f & 1) * 32 + (ln >> 4) * 8;
        uint4 w;
        w.x = pack2(f2bf(Ls[n][kb8 + 0]), f2bf(Ls[n][kb8 + 1]));
        w.y = pack2(f2bf(Ls[n][kb8 + 2]), f2bf(Ls[n][kb8 + 3]));
        w.z = pack2(f2bf(Ls[n][kb8 + 4]), f2bf(Ls[n][kb8 + 5]));
        w.w = pack2(f2bf(Ls[n][kb8 + 6]), f2bf(Ls[n][kb8 + 7]));
        size_t off = ((size_t)(kc * 24 + mat * 8 + f) * 64 + ln) * 8;
        *reinterpret_cast<uint4*>(&wt[off]) = w;
    }
}

// ---------------------------------------------------------------------------
// Fused QKV projection — r13 structure (known-fast codegen). ONLY change vs
// r13: the k output is stored as MFMA FRAGMENTS (kfb) instead of row-major.
// Same one-pass 50KB merge, same Stg staging, same store count (r14/r17
// lesson: any deeper epilogue restructure flips codegen — do NOT touch).
// Emits: q row-major (pre-scaled), kfb fragment-major, v transposed vt[b][h][t].
// ---------------------------------------------------------------------------
__global__ __launch_bounds__(512, 1)
void proj_kernel(const float* __restrict__ x, const unsigned short* __restrict__ wt,
                 const float* __restrict__ bq, const float* __restrict__ bk,
                 const float* __restrict__ bv,
                 unsigned short* __restrict__ qb, unsigned short* __restrict__ kfb,
                 unsigned short* __restrict__ vtb)
{
    const int tid = threadIdx.x;
    const int lane = tid & 63, wv = tid >> 6;   // wv 0..7
    const int l15 = lane & 15, lg = lane >> 4;
    const int kof = lg * 8;

    const int rg = wv & 3;                      // row-group (= ct quarter)
    const int kh = wv >> 2;                     // k-half
    const int m0    = blockIdx.x * 64 + rg * 16;
    const int batch = m0 >> 12;
    const int t0    = m0 & (T_CTX - 1);
    const int tt    = blockIdx.x & 63;          // 64-row tile index in batch
    const int kbeg  = kh * 512;

    f32x4 acc[3][4] = {};
    const float* xrow = &x[(size_t)(m0 + l15) * E_DIM + kof];
    const unsigned short* wlane = wt + (size_t)lane * 8;   // lane-folded

    float4 xa0 = *reinterpret_cast<const float4*>(xrow + kbeg);
    float4 xb0 = *reinterpret_cast<const float4*>(xrow + kbeg + 4);
    float4 xa1 = *reinterpret_cast<const float4*>(xrow + kbeg + 32);
    float4 xb1 = *reinterpret_cast<const float4*>(xrow + kbeg + 36);

    for (int k0 = kbeg; k0 < kbeg + 512; k0 += 32) {
        const int kn = (k0 + 64 < kbeg + 512) ? k0 + 64 : kbeg;
        float4 na = *reinterpret_cast<const float4*>(xrow + kn);
        float4 nb = *reinterpret_cast<const float4*>(xrow + kn + 4);

        const int fb = (k0 >> 6) * 24 + ((k0 >> 5) & 1);
        short8_t bf[12];
        #pragma unroll
        for (int mat = 0; mat < 3; ++mat)
            #pragma unroll
            for (int oc = 0; oc < 4; ++oc)
                bf[mat * 4 + oc] = *reinterpret_cast<const short8_t*>(
                    wlane + (size_t)(fb + mat * 8 + oc * 2) * 512);

        uint4 au;
        au.x = cvtpk(xa0.x, xa0.y); au.y = cvtpk(xa0.z, xa0.w);
        au.z = cvtpk(xb0.x, xb0.y); au.w = cvtpk(xb0.z, xb0.w);
        const short8_t a = __builtin_bit_cast(short8_t, au);

        #pragma unroll
        for (int mat = 0; mat < 3; ++mat)
            #pragma unroll
            for (int oc = 0; oc < 4; ++oc)
                acc[mat][oc] = __builtin_amdgcn_mfma_f32_16x16x32_bf16(
                    a, bf[mat * 4 + oc], acc[mat][oc], 0, 0, 0);

        xa0 = xa1; xb0 = xb1; xa1 = na; xb1 = nb;
    }

    __shared__ float Ms[4][64][49];              // 50 KB fp32 merge (one pass)
    __shared__ unsigned short Stg[4][1024];      // 8 KB bf16 staging (NO alias)
    if (kh == 1) {
        #pragma unroll
        for (int mat = 0; mat < 3; ++mat)
            #pragma unroll
            for (int oc = 0; oc < 4; ++oc)
                #pragma unroll
                for (int r = 0; r < 4; ++r)
                    Ms[rg][lane][(mat * 4 + oc) * 4 + r] = acc[mat][oc][r];
    }
    __syncthreads();
    if (kh == 0) {
        #pragma unroll
        for (int mat = 0; mat < 3; ++mat)
            #pragma unroll
            for (int oc = 0; oc < 4; ++oc)
                #pragma unroll
                for (int r = 0; r < 4; ++r)
                    acc[mat][oc][r] += Ms[rg][lane][(mat * 4 + oc) * 4 + r];

        unsigned short* stage = &Stg[rg][0];

        // ---- q: stage swizzled -> coalesced row-major write ----
        #pragma unroll
        for (int oc = 0; oc < 4; ++oc) {
            const float bb = bq[oc * 16 + l15];
            #pragma unroll
            for (int r = 0; r < 4; ++r)
                stage[swz(lg * 4 + r, oc * 16 + l15)] =
                    f2bf((acc[0][oc][r] + bb) * SCALE_Q);
        }
        {
            const int row = lane >> 2, c = (lane & 3) * 16;
            uint4 w0 = *reinterpret_cast<const uint4*>(&stage[swz(row, c)]);
            uint4 w1 = *reinterpret_cast<const uint4*>(&stage[swz(row, c + 8)]);
            *reinterpret_cast<uint4*>(&qb[(size_t)(m0 + row) * H_DIM + c]) = w0;
            *reinterpret_cast<uint4*>(&qb[(size_t)(m0 + row) * H_DIM + c + 8]) = w1;
        }

        // ---- k: stage swizzled -> 2 FRAGMENT stores (this rg == ct) ----
        #pragma unroll
        for (int oc = 0; oc < 4; ++oc) {
            const float bb = bk[oc * 16 + l15];
            #pragma unroll
            for (int r = 0; r < 4; ++r)
                stage[swz(lg * 4 + r, oc * 16 + l15)] =
                    f2bf(acc[1][oc][r] + bb);
        }
        #pragma unroll
        for (int hs = 0; hs < 2; ++hs) {
            uint4 w = *reinterpret_cast<const uint4*>(&stage[swz(l15, hs * 32 + kof)]);
            *reinterpret_cast<uint4*>(
                &kfb[(((size_t)batch * 64 + tt) * 8 + hs * 4 + rg) * 512 + lane * 8]) = w;
        }

        // ---- v: transposed rows vt[b][h][t] (r13 pattern) ----
        #pragma unroll
        for (int oc = 0; oc < 4; ++oc) {
            const float bb = bv[oc * 16 + l15];
            const int h = oc * 16 + l15;
            uint2 pw;
            pw.x = cvtpk(acc[2][oc][0] + bb, acc[2][oc][1] + bb);
            pw.y = cvtpk(acc[2][oc][2] + bb, acc[2][oc][3] + bb);
            *reinterpret_cast<uint2*>(&stage[h * 16 + lg * 4]) = pw;
        }
        const int h = lane;
        uint4 v0 = *reinterpret_cast<const uint4*>(&stage[h * 16]);
        uint4 v1 = *reinterpret_cast<const uint4*>(&stage[h * 16 + 8]);
        unsigned short* vrow = &vtb[((size_t)batch * H_DIM + h) * T_CTX + t0];
        *reinterpret_cast<uint4*>(&vrow[0]) = v0;
        *reinterpret_cast<uint4*>(&vrow[8]) = v1;
    }
}

// ---------------------------------------------------------------------------
// Repack V only: vt[b][h][t] -> fragment-major vfb (1KB wave-streams).
// ---------------------------------------------------------------------------
__global__ __launch_bounds__(512)
void repack_v(const unsigned short* __restrict__ vtb,
              unsigned short* __restrict__ vfb)
{
    const int b  = blockIdx.x >> 6;
    const int tt = blockIdx.x & 63;
    const int tid = threadIdx.x;
    const int lane = tid & 63, wv = tid >> 6;
    const int l15 = lane & 15, lg = lane >> 4;
    const int kof = lg * 8;

    __shared__ unsigned short Vt[64 * 64];   // [h][t_local] swizzled

    {
        const int row = tid >> 3;            // h = 0..63
        const int c8  = (tid & 7) * 8;       // t_local
        uint4 vw = *reinterpret_cast<const uint4*>(
            &vtb[((size_t)b * H_DIM + row) * T_CTX + tt * 64 + c8]);
        *reinterpret_cast<uint4*>(&Vt[swz(row, c8)]) = vw;
    }
    __syncthreads();

    {
        const int g = wv;                    // 0..7 = oc*2 + ks
        const int oc = g >> 1, ks = g & 1;
        uint4 vw = *reinterpret_cast<const uint4*>(
            &Vt[swz(oc * 16 + l15, ks * 32 + kof)]);
        *reinterpret_cast<uint4*>(
            &vfb[(((size_t)b * 64 + tt) * 8 + g) * 512 + lane * 8]) = vw;
    }
}

// ---------------------------------------------------------------------------
// Causal flash attention — complementary-pair schedule, fragment-major K/V
// (every load = contiguous 1KB wave-stream). Passing at ~13us.
// ---------------------------------------------------------------------------
__global__ __launch_bounds__(512)
void attn_kernel(const unsigned short* __restrict__ qg,
                 const unsigned short* __restrict__ kfb,
                 const unsigned short* __restrict__ vfb,
                 float* __restrict__ outp)
{
    const int tid  = threadIdx.x;
    const int lane = tid & 63, wv = tid >> 6;   // wv 0..7
    const int l15 = lane & 15, lg = lane >> 4;
    const int kof = lg * 8;

    __shared__ float smem[8448];                // Pt (32KB) ∪ merge (33KB)
    unsigned short* Pt = (unsigned short*)smem;
    const int pbase = wv * 2048;                // per-wave [32][64] bf16

    #pragma unroll 1
    for (int half = 0; half < 2; ++half) {
        const int r     = half ? (511 - (int)blockIdx.x) : (int)blockIdx.x;
        const int st    = 127 - (r >> 2);
        const int batch = r & 3;
        const int q0    = st * 32;
        const int nkv   = st / 2 + 1;           // 64-wide kv tiles
        const size_t rbase = (size_t)batch * T_CTX;
        const size_t fbase = (size_t)(batch * 64) * 8 * 512 + (size_t)lane * 8;

        __syncthreads();   // previous unit's merge reads done before Pt reuse

        short8_t qlo[2], qhi[2];
        #pragma unroll
        for (int hs = 0; hs < 2; ++hs) {
            qlo[hs] = *reinterpret_cast<const short8_t*>(
                &qg[(rbase + q0 + l15) * H_DIM + hs * 32 + kof]);
            qhi[hs] = *reinterpret_cast<const short8_t*>(
                &qg[(rbase + q0 + 16 + l15) * H_DIM + hs * 32 + kof]);
        }

        f32x4 olo[4] = {}, ohi[4] = {};
        float mlo = -1e30f, mhi = -1e30f, llo = 0.f, lhi = 0.f;

        // 1-deep K prefetch: kfC holds tile t's K fragments (contiguous loads)
        short8_t kfC[8];
        if (wv < nkv) {
            const unsigned short* kp = kfb + fbase + (size_t)wv * 8 * 512;
            #pragma unroll
            for (int i = 0; i < 8; ++i)
                kfC[i] = *reinterpret_cast<const short8_t*>(kp + i * 512);
        }

        for (int t = wv; t < nkv; t += 8) {
            const int k0 = t * 64;

            // V fragments issued EARLY (consumed after softmax)
            const unsigned short* vp = vfb + fbase + (size_t)t * 8 * 512;
            short8_t vf[8];
            #pragma unroll
            for (int g = 0; g < 8; ++g)
                vf[g] = *reinterpret_cast<const short8_t*>(vp + g * 512);

            // next tile's K issued EARLY (consumed next iteration)
            short8_t kfN[8];
            const bool havN = (t + 8 < nkv);
            if (havN) {
                const unsigned short* kp = kfb + fbase + (size_t)(t + 8) * 8 * 512;
                #pragma unroll
                for (int i = 0; i < 8; ++i)
                    kfN[i] = *reinterpret_cast<const short8_t*>(kp + i * 512);
            }

            f32x4 slo[4] = {}, shi[4] = {};
            #pragma unroll
            for (int hs = 0; hs < 2; ++hs)
                #pragma unroll
                for (int ct = 0; ct < 4; ++ct) {
                    slo[ct] = __builtin_amdgcn_mfma_f32_16x16x32_bf16(
                        kfC[hs * 4 + ct], qlo[hs], slo[ct], 0, 0, 0);
                    shi[ct] = __builtin_amdgcn_mfma_f32_16x16x32_bf16(
                        kfC[hs * 4 + ct], qhi[hs], shi[ct], 0, 0, 0);
                }

            if (t == nkv - 1) {   // only the strip's last tile crosses the diagonal
                #pragma unroll
                for (int ct = 0; ct < 4; ++ct)
                    #pragma unroll
                    for (int rr = 0; rr < 4; ++rr) {
                        const int kv = k0 + ct * 16 + lg * 4 + rr;
                        if (kv > q0 + l15)      slo[ct][rr] = -1e30f;
                        if (kv > q0 + 16 + l15) shi[ct][rr] = -1e30f;
                    }
            }

            float mxlo, mxhi;
            {
                float a = fmaxf(fmaxf(slo[0][0], slo[0][1]), fmaxf(slo[0][2], slo[0][3]));
                float b = fmaxf(fmaxf(slo[1][0], slo[1][1]), fmaxf(slo[1][2], slo[1][3]));
                float c = fmaxf(fmaxf(slo[2][0], slo[2][1]), fmaxf(slo[2][2], slo[2][3]));
                float d = fmaxf(fmaxf(slo[3][0], slo[3][1]), fmaxf(slo[3][2], slo[3][3]));
                mxlo = fmaxf(fmaxf(a, b), fmaxf(c, d));
                a = fmaxf(fmaxf(shi[0][0], shi[0][1]), fmaxf(shi[0][2], shi[0][3]));
                b = fmaxf(fmaxf(shi[1][0], shi[1][1]), fmaxf(shi[1][2], shi[1][3]));
                c = fmaxf(fmaxf(shi[2][0], shi[2][1]), fmaxf(shi[2][2], shi[2][3]));
                d = fmaxf(fmaxf(shi[3][0], shi[3][1]), fmaxf(shi[3][2], shi[3][3]));
                mxhi = fmaxf(fmaxf(a, b), fmaxf(c, d));
            }
            mxlo = fmaxf(mxlo, __shfl_xor(mxlo, 16));
            mxlo = fmaxf(mxlo, __shfl_xor(mxlo, 32));
            mxhi = fmaxf(mxhi, __shfl_xor(mxhi, 16));
            mxhi = fmaxf(mxhi, __shfl_xor(mxhi, 32));

            if (!__all((mxlo <= mlo + DEFER_THR) && (mxhi <= mhi + DEFER_THR))) {
                const float nmlo = fmaxf(mlo, mxlo), nmhi = fmaxf(mhi, mxhi);
                const float cflo = fexp2(mlo - nmlo), cfhi = fexp2(mhi - nmhi);
                llo *= cflo; lhi *= cfhi;
                mlo = nmlo; mhi = nmhi;
                #pragma unroll
                for (int rr = 0; rr < 4; ++rr) {
                    const float cl = __shfl(cflo, lg * 4 + rr);
                    const float ch = __shfl(cfhi, lg * 4 + rr);
                    #pragma unroll
                    for (int oc = 0; oc < 4; ++oc) { olo[oc][rr] *= cl; ohi[oc][rr] *= ch; }
                }
            }

            float rllo = 0.f, rlhi = 0.f;
            #pragma unroll
            for (int ct = 0; ct < 4; ++ct) {
                const float p0 = fexp2(slo[ct][0] - mlo), p1 = fexp2(slo[ct][1] - mlo);
                const float p2 = fexp2(slo[ct][2] - mlo), p3 = fexp2(slo[ct][3] - mlo);
                rllo += (p0 + p1) + (p2 + p3);
                uint2 pw; pw.x = cvtpk(p0, p1); pw.y = cvtpk(p2, p3);
                *reinterpret_cast<uint2*>(&Pt[pbase + swz(l15, ct * 16 + lg * 4)]) = pw;
                const float h0 = fexp2(shi[ct][0] - mhi), h1 = fexp2(shi[ct][1] - mhi);
                const float h2 = fexp2(shi[ct][2] - mhi), h3 = fexp2(shi[ct][3] - mhi);
                rlhi += (h0 + h1) + (h2 + h3);
                uint2 ph; ph.x = cvtpk(h0, h1); ph.y = cvtpk(h2, h3);
                *reinterpret_cast<uint2*>(&Pt[pbase + swz(16 + l15, ct * 16 + lg * 4)]) = ph;
            }
            rllo += __shfl_xor(rllo, 16); rllo += __shfl_xor(rllo, 32);
            rlhi += __shfl_xor(rlhi, 16); rlhi += __shfl_xor(rlhi, 32);
            llo += rllo; lhi += rlhi;

            #pragma unroll
            for (int ks = 0; ks < 2; ++ks) {
                const short8_t palo = *reinterpret_cast<const short8_t*>(
                    &Pt[pbase + swz(l15, ks * 32 + kof)]);
                const short8_t pahi = *reinterpret_cast<const short8_t*>(
                    &Pt[pbase + swz(16 + l15, ks * 32 + kof)]);
                #pragma unroll
                for (int oc = 0; oc < 4; ++oc) {
                    olo[oc] = __builtin_amdgcn_mfma_f32_16x16x32_bf16(
                        palo, vf[oc * 2 + ks], olo[oc], 0, 0, 0);
                    ohi[oc] = __builtin_amdgcn_mfma_f32_16x16x32_bf16(
                        pahi, vf[oc * 2 + ks], ohi[oc], 0, 0, 0);
                }
            }

            if (havN) {
                #pragma unroll
                for (int i = 0; i < 8; ++i) kfC[i] = kfN[i];
            }
        }

        // ---- two-phase merge + DIRECT output: ph 0 = lo rows, 1 = hi rows ----
        #pragma unroll 1
        for (int ph = 0; ph < 2; ++ph) {
            __syncthreads();
            #pragma unroll
            for (int oc = 0; oc < 4; ++oc)
                #pragma unroll
                for (int rr = 0; rr < 4; ++rr)
                    smem[wv * 1024 + (lg * 4 + rr) * 64 + oc * 16 + l15] =
                        ph ? ohi[oc][rr] : olo[oc][rr];
            if (lg == 0) {
                smem[8192 + wv * 16 + l15] = ph ? mhi : mlo;
                smem[8320 + wv * 16 + l15] = ph ? lhi : llo;
            }
            __syncthreads();
            const int row = tid >> 5;          // 0..15
            const int c2  = (tid & 31) * 2;
            float M = -1e30f;
            #pragma unroll
            for (int w = 0; w < 8; ++w) M = fmaxf(M, smem[8192 + w * 16 + row]);
            float L = 0.f, a0 = 0.f, a1 = 0.f;
            #pragma unroll
            for (int w = 0; w < 8; ++w) {
                const float e = fexp2(smem[8192 + w * 16 + row] - M);
                L += e * smem[8320 + w * 16 + row];
                a0 += e * smem[w * 1024 + row * 64 + c2];
                a1 += e * smem[w * 1024 + row * 64 + c2 + 1];
            }
            const float inv = 1.0f / L;
            float2 rr2; rr2.x = a0 * inv; rr2.y = a1 * inv;
            *reinterpret_cast<float2*>(
                &outp[(rbase + q0 + ph * 16 + row) * H_DIM + c2]) = rr2;
        }
    }
}

extern "C" void kernel_launch(void* const* d_in, const int* in_sizes, int n_in,
                              void* d_out, int out_size, void* d_ws, size_t ws_size,
                              hipStream_t stream) {
    const float* x  = (const float*)d_in[0];
    const float* Wq = (const float*)d_in[1];
    const float* bq = (const float*)d_in[2];
    const float* Wk = (const float*)d_in[3];
    const float* bk = (const float*)d_in[4];
    const float* Wv = (const float*)d_in[5];
    const float* bv = (const float*)d_in[6];
    float* out = (float*)d_out;

    // ws (ushort): wt | qb | kfb | vtb | vfb  (~8.8 MB)
    unsigned short* wt  = (unsigned short*)d_ws;
    unsigned short* qb  = wt  + 3 * H_DIM * E_DIM;
    unsigned short* kfb = qb  + (size_t)M_ROWS * H_DIM;
    unsigned short* vtb = kfb + (size_t)M_ROWS * H_DIM;
    unsigned short* vfb = vtb + (size_t)B_SZ * H_DIM * T_CTX;

    prep_weights<<<dim3(E_DIM / 64, 3), 256, 0, stream>>>(Wq, Wk, Wv, wt);
    proj_kernel<<<dim3(M_ROWS / 64), 512, 0, stream>>>(x, wt, bq, bk, bv, qb, kfb, vtb);
    repack_v<<<dim3(B_SZ * 64), 512, 0, stream>>>(vtb, vfb);
    attn_kernel<<<dim3(256), 512, 0, stream>>>(qb, kfb, vfb, out);
}